// Round 2
// baseline (425.740 us; speedup 1.0000x reference)
//
#include <hip/hip_runtime.h>
#include <cstdint>
#include <cstddef>

// Pipeline v6. B=4, T=2048, D=1024, H=16, HD=64. Inputs fp32, output fp32.
// attn v5: no K/V LDS staging, no barriers (kept from v4-attempt), but with
// REGISTER double-buffering to restore latency hiding:
//   - V^T frags for tile kt issued at top of iteration, consumed ~400cy later
//   - K frags for tile kt+1 prefetched right after QK^T consumes current ones
// V stored pre-transposed [bh][d][t] by QKV epilogue. Only LDS: per-wave P
// strip (8KB/block). XCD-clustered remap (XCD c owns heads 8c..8c+7).
// launch_bounds(256,3): ~170 VGPR cap, guaranteed no spill, 12 waves/CU.
// GEMMs unchanged (m97-style global_load_lds width-16 staging).

typedef __bf16 bf16;
typedef __bf16 bf16x4 __attribute__((ext_vector_type(4)));
typedef __bf16 bf16x8 __attribute__((ext_vector_type(8)));
typedef float  f32x4  __attribute__((ext_vector_type(4)));
typedef float  fvec4  __attribute__((ext_vector_type(4)));
typedef unsigned u32x4 __attribute__((ext_vector_type(4)));

typedef __attribute__((address_space(1))) const void global_cv;
typedef __attribute__((address_space(3))) void lds_v;

#define MFMA16(a, b, c) __builtin_amdgcn_mfma_f32_16x16x32_bf16((a), (b), (c), 0, 0, 0)

// Q scale: 1/sqrt(64) * log2(e)  (softmax done in exp2 domain)
#define QSCALE 0.18033688f

__device__ __forceinline__ void async_ld16(const bf16* g, bf16* l) {
  // gfx950 16B direct global->LDS; dest = wave-uniform base + lane*16.
  __builtin_amdgcn_global_load_lds((global_cv*)g, (lds_v*)l, 16, 0, 0);
}

// XOR chunk swizzle for [rows][64] bf16 LDS tiles.
__device__ __forceinline__ int swz_off(int row, int col) {
  int sr = (row & 7) ^ ((row >> 3) & 7);
  return row * 64 + ((((col >> 3) ^ sr) & 7) * 8) + (col & 7);
}

__device__ __forceinline__ bf16x8 cvt8(const float* p) {
  fvec4 u = *(const fvec4*)p;
  fvec4 v = *(const fvec4*)(p + 4);
  bf16x8 r;
  r[0] = (bf16)u[0]; r[1] = (bf16)u[1]; r[2] = (bf16)u[2]; r[3] = (bf16)u[3];
  r[4] = (bf16)v[0]; r[5] = (bf16)v[1]; r[6] = (bf16)v[2]; r[7] = (bf16)v[3];
  return r;
}

// ---------------------------------------------------------------------------
// fp32 -> bf16 bulk convert (8 elems/thread).
// ---------------------------------------------------------------------------
__global__ void cvt_f32_bf16(const float* __restrict__ s, bf16* __restrict__ d,
                             int n8) {
  int i = blockIdx.x * 256 + threadIdx.x;
  if (i < n8) *(bf16x8*)(d + (size_t)i * 8) = cvt8(s + (size_t)i * 8);
}

// ---------------------------------------------------------------------------
// Shared epilogue: Q,K as [bh][t][64]; V TRANSPOSED as [bh][d][t].
// ---------------------------------------------------------------------------
__device__ __forceinline__ void qkv_scatter(const f32x4 acc[4][4], int m0, int n0,
                                            int wm, int wn, int quad, int l15,
                                            bf16* Qo, bf16* Ko, bf16* Vo) {
  const int which = n0 >> 10;  // 0=Q 1=K 2=V
  if (which == 2) {
    // V^T: [bh][d][t]; 4 accumulator rows per lane are t-consecutive -> 8B store
#pragma unroll
    for (int i = 0; i < 4; ++i) {
      const int m = m0 + wm + i * 16 + quad * 4;  // multiple of 4, no b-crossing
      const int b = m >> 11;
      const int t = m & 2047;
#pragma unroll
      for (int j = 0; j < 4; ++j) {
        const int n1 = (n0 + wn + j * 16 + l15) & 1023;
        const int h  = n1 >> 6;
        const int d  = n1 & 63;
        bf16x4 v;
#pragma unroll
        for (int r = 0; r < 4; ++r) v[r] = (bf16)acc[i][j][r];
        *(bf16x4*)(Vo + ((size_t)(b * 16 + h) * 64 + d) * 2048 + t) = v;
      }
    }
    return;
  }
  bf16* dst = (which == 0) ? Qo : Ko;
  const float scale = (which == 0) ? QSCALE : 1.0f;
#pragma unroll
  for (int i = 0; i < 4; ++i) {
    const int m = m0 + wm + i * 16 + quad * 4;
#pragma unroll
    for (int j = 0; j < 4; ++j) {
      const int n  = n0 + wn + j * 16 + l15;
      const int n1 = n & 1023;
      const int h  = n1 >> 6;
      const int d  = n1 & 63;
#pragma unroll
      for (int r = 0; r < 4; ++r) {
        const int mm = m + r;
        const int b  = mm >> 11;
        const int t  = mm & 2047;
        dst[(((size_t)(b * 16 + h)) * 2048 + t) * 64 + d] =
            (bf16)(acc[i][j][r] * scale);
      }
    }
  }
}

// ---------------------------------------------------------------------------
// QKV GEMM, bf16 async-staging variant (plan A). grid (24,64).
// ---------------------------------------------------------------------------
__global__ __launch_bounds__(256, 2)
void gemm_qkv_a(const bf16* __restrict__ A, const bf16* __restrict__ B,
                bf16* __restrict__ Qo, bf16* __restrict__ Ko,
                bf16* __restrict__ Vo) {
  __shared__ __align__(16) bf16 As[128 * 32];
  __shared__ __align__(16) bf16 Bs[128 * 32];
  const int K = 1024;

  const int tid  = threadIdx.x;
  const int lane = tid & 63;
  const int wave = tid >> 6;
  const int quad = lane >> 4;
  const int l15  = lane & 15;
  const int wm   = (wave >> 1) * 64;
  const int wn   = (wave & 1) * 64;
  const int m0   = blockIdx.y * 128;
  const int n0   = blockIdx.x * 128;

  f32x4 acc[4][4];
#pragma unroll
  for (int i = 0; i < 4; ++i)
#pragma unroll
    for (int j = 0; j < 4; ++j) acc[i][j] = f32x4{0.f, 0.f, 0.f, 0.f};

  const int r0 = tid >> 2;
  const int c0 = (tid & 3) * 8;
  const bf16* ag0 = A + (size_t)(m0 + r0) * K + c0;
  const bf16* ag1 = A + (size_t)(m0 + 64 + r0) * K + c0;
  const bf16* bg0 = B + (size_t)(n0 + r0) * K + c0;
  const bf16* bg1 = B + (size_t)(n0 + 64 + r0) * K + c0;
  const int lo0 = (wave * 64) * 8;        // wave-uniform LDS elem offset
  const int lo1 = (256 + wave * 64) * 8;

  for (int k0 = 0; k0 < K; k0 += 32) {
    __syncthreads();
    async_ld16(ag0 + k0, As + lo0);
    async_ld16(ag1 + k0, As + lo1);
    async_ld16(bg0 + k0, Bs + lo0);
    async_ld16(bg1 + k0, Bs + lo1);
    __syncthreads();

    bf16x8 af[4], bfr[4];
#pragma unroll
    for (int i = 0; i < 4; ++i)
      af[i] = *(const bf16x8*)(As + (wm + i * 16 + l15) * 32 + quad * 8);
#pragma unroll
    for (int j = 0; j < 4; ++j)
      bfr[j] = *(const bf16x8*)(Bs + (wn + j * 16 + l15) * 32 + quad * 8);
#pragma unroll
    for (int i = 0; i < 4; ++i)
#pragma unroll
      for (int j = 0; j < 4; ++j)
        acc[i][j] = MFMA16(af[i], bfr[j], acc[i][j]);
  }
  qkv_scatter(acc, m0, n0, wm, wn, quad, l15, Qo, Ko, Vo);
}

// ---------------------------------------------------------------------------
// QKV GEMM, fp32 cvt8 register-staging variant (plan B fallback). grid (24,64).
// ---------------------------------------------------------------------------
__global__ __launch_bounds__(256, 2)
void gemm_qkv_f(const float* __restrict__ A, const float* __restrict__ B,
                bf16* __restrict__ Qo, bf16* __restrict__ Ko,
                bf16* __restrict__ Vo) {
  __shared__ __align__(16) bf16 As[128 * 32];
  __shared__ __align__(16) bf16 Bs[128 * 32];
  const int K = 1024;

  const int tid  = threadIdx.x;
  const int lane = tid & 63;
  const int wave = tid >> 6;
  const int quad = lane >> 4;
  const int l15  = lane & 15;
  const int wm   = (wave >> 1) * 64;
  const int wn   = (wave & 1) * 64;
  const int m0   = blockIdx.y * 128;
  const int n0   = blockIdx.x * 128;

  f32x4 acc[4][4];
#pragma unroll
  for (int i = 0; i < 4; ++i)
#pragma unroll
    for (int j = 0; j < 4; ++j) acc[i][j] = f32x4{0.f, 0.f, 0.f, 0.f};

  const int r0 = tid >> 2;
  const int c0 = (tid & 3) * 8;
  const size_t aoff0 = (size_t)(m0 + r0) * K + c0;
  const size_t aoff1 = (size_t)(m0 + 64 + r0) * K + c0;
  const size_t boff0 = (size_t)(n0 + r0) * K + c0;
  const size_t boff1 = (size_t)(n0 + 64 + r0) * K + c0;

  for (int k0 = 0; k0 < K; k0 += 32) {
    bf16x8 va0 = cvt8(A + aoff0 + k0);
    bf16x8 va1 = cvt8(A + aoff1 + k0);
    bf16x8 vb0 = cvt8(B + boff0 + k0);
    bf16x8 vb1 = cvt8(B + boff1 + k0);
    __syncthreads();
    *(bf16x8*)(As + tid * 8)        = va0;
    *(bf16x8*)(As + 2048 + tid * 8) = va1;
    *(bf16x8*)(Bs + tid * 8)        = vb0;
    *(bf16x8*)(Bs + 2048 + tid * 8) = vb1;
    __syncthreads();

    bf16x8 af[4], bfr[4];
#pragma unroll
    for (int i = 0; i < 4; ++i)
      af[i] = *(const bf16x8*)(As + (wm + i * 16 + l15) * 32 + quad * 8);
#pragma unroll
    for (int j = 0; j < 4; ++j)
      bfr[j] = *(const bf16x8*)(Bs + (wn + j * 16 + l15) * 32 + quad * 8);
#pragma unroll
    for (int i = 0; i < 4; ++i)
#pragma unroll
      for (int j = 0; j < 4; ++j)
        acc[i][j] = MFMA16(af[i], bfr[j], acc[i][j]);
  }
  qkv_scatter(acc, m0, n0, wm, wn, quad, l15, Qo, Ko, Vo);
}

// ---------------------------------------------------------------------------
// Flash attention v5, causal. grid (16,64) remapped so XCD c (= lin%8) owns
// heads 8c..8c+7; block handles q-tiles {p, 31-p} (balanced: 33 kv-tiles).
// K and V^T frags from global with REGISTER double-buffering:
//   vf (current tile) issued at top, consumed after softmax (~400cy gap)
//   kf prefetched one tile ahead, right after QK^T consumes current kf
// Only LDS: per-wave P strip (swizzled). No __syncthreads; waves independent.
// No-max softmax in exp2 domain (log2e folded into Q scale); per-lane l
// accumulated across tiles, single 16-lane reduce at the end.
// ---------------------------------------------------------------------------
__global__ __launch_bounds__(256, 3)
void attn(const bf16* __restrict__ Q, const bf16* __restrict__ Kk,
          const bf16* __restrict__ Vt, bf16* __restrict__ Y) {
  __shared__ __align__(16) bf16 Ps[4 * 16 * 64];   // per-wave P strips, 8KB

  const int tid  = threadIdx.x;
  const int wave = tid >> 6;
  const int lane = tid & 63;
  const int quad = lane >> 4;
  const int l15  = lane & 15;

  // XCD-clustered remap: lin%8 = XCD; each XCD gets heads [8c, 8c+8).
  const int lin  = (int)blockIdx.x + ((int)blockIdx.y << 4);
  const int slot = lin >> 3;                 // 0..127 within XCD
  const int bh   = (lin & 7) * 8 + (slot >> 4);
  const int p    = slot & 15;
  const int b    = bh >> 4;
  const int h    = bh & 15;

  const bf16* Qb = Q  + (size_t)bh * (2048 * 64);
  const bf16* Kb = Kk + (size_t)bh * (2048 * 64);   // [t][64]
  const bf16* Vb = Vt + (size_t)bh * (2048 * 64);   // [64][2048] (transposed)
  bf16* Pw = Ps + wave * (16 * 64);

  // per-lane fragment base pointers
  const bf16* kl = Kb + (size_t)l15 * 64 + quad * 8;     // + (k0+j*16)*64 (+32)
  const bf16* vl = Vb + (size_t)l15 * 2048 + quad * 8;   // + j*16*2048 + k0 (+32)

  const float NEG = -1e30f;

#pragma unroll 1
  for (int pass = 0; pass < 2; ++pass) {
    const int qt = pass ? (31 - p) : p;
    const int q0 = qt * 64;

    const bf16* qp = Qb + (size_t)(q0 + wave * 16 + l15) * 64 + quad * 8;
    bf16x8 qa0 = *(const bf16x8*)qp;
    bf16x8 qa1 = *(const bf16x8*)(qp + 32);

    f32x4 l_run = {0.f, 0.f, 0.f, 0.f};
    f32x4 o[4];
#pragma unroll
    for (int j = 0; j < 4; ++j) o[j] = f32x4{0.f, 0.f, 0.f, 0.f};

    // preload K frags for tile 0
    bf16x8 kf0[4], kf1[4];
#pragma unroll
    for (int j = 0; j < 4; ++j) {
      const bf16* kp = kl + (size_t)(j * 16) * 64;
      kf0[j] = *(const bf16x8*)kp;
      kf1[j] = *(const bf16x8*)(kp + 32);
    }

#pragma unroll 1
    for (int kt = 0; kt <= qt; ++kt) {
      const int k0 = kt * 64;

      // V^T frags for CURRENT tile: issue now, consumed after softmax.
      bf16x8 vf0[4], vf1[4];
#pragma unroll
      for (int j = 0; j < 4; ++j) {
        const bf16* vp = vl + (size_t)j * (16 * 2048) + k0;
        vf0[j] = *(const bf16x8*)vp;
        vf1[j] = *(const bf16x8*)(vp + 32);
      }

      // S = Q K^T (log2 domain via QSCALE); consumes kf
      f32x4 s[4];
#pragma unroll
      for (int j = 0; j < 4; ++j) {
        f32x4 z = {0.f, 0.f, 0.f, 0.f};
        z = MFMA16(qa0, kf0[j], z);
        z = MFMA16(qa1, kf1[j], z);
        s[j] = z;
      }

      // prefetch K frags for NEXT tile (kf regs now free)
      if (kt < qt) {
        const int kn = k0 + 64;
#pragma unroll
        for (int j = 0; j < 4; ++j) {
          const bf16* kp = kl + (size_t)(kn + j * 16) * 64;
          kf0[j] = *(const bf16x8*)kp;
          kf1[j] = *(const bf16x8*)(kp + 32);
        }
      }

      if (kt == qt) {  // diagonal: causal mask
#pragma unroll
        for (int j = 0; j < 4; ++j) {
          const int kvg = k0 + j * 16 + l15;
#pragma unroll
          for (int r = 0; r < 4; ++r) {
            const int qg = q0 + wave * 16 + quad * 4 + r;
            if (kvg > qg) s[j][r] = NEG;
          }
        }
      }

      // p = exp2(s); accumulate per-lane l partials
#pragma unroll
      for (int j = 0; j < 4; ++j)
#pragma unroll
        for (int r = 0; r < 4; ++r) {
          float pv = exp2f(s[j][r]);
          s[j][r] = pv;
          l_run[r] += pv;
        }

      // P: C-layout -> per-wave LDS strip -> A-operand frags
#pragma unroll
      for (int j = 0; j < 4; ++j)
#pragma unroll
        for (int r = 0; r < 4; ++r)
          Pw[swz_off(quad * 4 + r, j * 16 + l15)] = (bf16)s[j][r];

      bf16x8 pf0 = *(const bf16x8*)(Pw + swz_off(l15, quad * 8));
      bf16x8 pf1 = *(const bf16x8*)(Pw + swz_off(l15, 32 + quad * 8));

      // PV: consumes vf (issued at top of this iteration)
#pragma unroll
      for (int j = 0; j < 4; ++j) {
        o[j] = MFMA16(pf0, vf0[j], o[j]);
        o[j] = MFMA16(pf1, vf1[j], o[j]);
      }
    }

    // one deferred 16-lane reduce for l (lanes of a quad hold same rows)
#pragma unroll
    for (int msk = 1; msk < 16; msk <<= 1)
#pragma unroll
      for (int r = 0; r < 4; ++r) l_run[r] += __shfl_xor(l_run[r], msk);

#pragma unroll
    for (int j = 0; j < 4; ++j) {
      const int dcol = h * 64 + j * 16 + l15;
#pragma unroll
      for (int r = 0; r < 4; ++r) {
        const int trow = q0 + wave * 16 + quad * 4 + r;
        Y[((size_t)b * 2048 + trow) * 1024 + dcol] = (bf16)(o[j][r] / l_run[r]);
      }
    }
  }
}

// ---------------------------------------------------------------------------
// Projection GEMM, bf16 async variant (plan A): out fp32 = y(bf16)*wpb^T.
// grid (8,64).
// ---------------------------------------------------------------------------
__global__ __launch_bounds__(256, 2)
void gemm_proj_a(const bf16* __restrict__ A, const bf16* __restrict__ B,
                 float* __restrict__ C) {
  __shared__ __align__(16) bf16 As[128 * 32];
  __shared__ __align__(16) bf16 Bs[128 * 32];
  const int K = 1024, N = 1024;

  const int tid  = threadIdx.x;
  const int lane = tid & 63;
  const int wave = tid >> 6;
  const int quad = lane >> 4;
  const int l15  = lane & 15;
  const int wm   = (wave >> 1) * 64;
  const int wn   = (wave & 1) * 64;
  const int m0   = blockIdx.y * 128;
  const int n0   = blockIdx.x * 128;

  f32x4 acc[4][4];
#pragma unroll
  for (int i = 0; i < 4; ++i)
#pragma unroll
    for (int j = 0; j < 4; ++j) acc[i][j] = f32x4{0.f, 0.f, 0.f, 0.f};

  const int r0 = tid >> 2;
  const int c0 = (tid & 3) * 8;
  const bf16* ag0 = A + (size_t)(m0 + r0) * K + c0;
  const bf16* ag1 = A + (size_t)(m0 + 64 + r0) * K + c0;
  const bf16* bg0 = B + (size_t)(n0 + r0) * K + c0;
  const bf16* bg1 = B + (size_t)(n0 + 64 + r0) * K + c0;
  const int lo0 = (wave * 64) * 8;
  const int lo1 = (256 + wave * 64) * 8;

  for (int k0 = 0; k0 < K; k0 += 32) {
    __syncthreads();
    async_ld16(ag0 + k0, As + lo0);
    async_ld16(ag1 + k0, As + lo1);
    async_ld16(bg0 + k0, Bs + lo0);
    async_ld16(bg1 + k0, Bs + lo1);
    __syncthreads();

    bf16x8 af[4], bfr[4];
#pragma unroll
    for (int i = 0; i < 4; ++i)
      af[i] = *(const bf16x8*)(As + (wm + i * 16 + l15) * 32 + quad * 8);
#pragma unroll
    for (int j = 0; j < 4; ++j)
      bfr[j] = *(const bf16x8*)(Bs + (wn + j * 16 + l15) * 32 + quad * 8);
#pragma unroll
    for (int i = 0; i < 4; ++i)
#pragma unroll
      for (int j = 0; j < 4; ++j)
        acc[i][j] = MFMA16(af[i], bfr[j], acc[i][j]);
  }

#pragma unroll
  for (int i = 0; i < 4; ++i) {
    const int m = m0 + wm + i * 16 + quad * 4;
#pragma unroll
    for (int j = 0; j < 4; ++j) {
      const int n = n0 + wn + j * 16 + l15;
#pragma unroll
      for (int r = 0; r < 4; ++r)
        C[(size_t)(m + r) * N + n] = acc[i][j][r];
    }
  }
}

// ---------------------------------------------------------------------------
// Projection GEMM, fp32-B fallback (plan B). grid (8,64).
// ---------------------------------------------------------------------------
__global__ __launch_bounds__(256, 2)
void gemm_proj_f(const bf16* __restrict__ A, const float* __restrict__ B,
                 float* __restrict__ C) {
  __shared__ __align__(16) bf16 As[128 * 32];
  __shared__ __align__(16) bf16 Bs[128 * 32];
  const int K = 1024, N = 1024;

  const int tid  = threadIdx.x;
  const int lane = tid & 63;
  const int wave = tid >> 6;
  const int quad = lane >> 4;
  const int l15  = lane & 15;
  const int wm   = (wave >> 1) * 64;
  const int wn   = (wave & 1) * 64;
  const int m0   = blockIdx.y * 128;
  const int n0   = blockIdx.x * 128;

  f32x4 acc[4][4];
#pragma unroll
  for (int i = 0; i < 4; ++i)
#pragma unroll
    for (int j = 0; j < 4; ++j) acc[i][j] = f32x4{0.f, 0.f, 0.f, 0.f};

  const int r0 = tid >> 2;
  const int c0 = (tid & 3) * 8;
  const size_t aoff0 = (size_t)(m0 + r0) * K + c0;
  const size_t aoff1 = (size_t)(m0 + 64 + r0) * K + c0;
  const size_t boff0 = (size_t)(n0 + r0) * K + c0;
  const size_t boff1 = (size_t)(n0 + 64 + r0) * K + c0;

  for (int k0 = 0; k0 < K; k0 += 32) {
    bf16x8 va0 = *(const bf16x8*)(A + aoff0 + k0);
    bf16x8 va1 = *(const bf16x8*)(A + aoff1 + k0);
    bf16x8 vb0 = cvt8(B + boff0 + k0);
    bf16x8 vb1 = cvt8(B + boff1 + k0);
    __syncthreads();
    *(bf16x8*)(As + tid * 8)        = va0;
    *(bf16x8*)(As + 2048 + tid * 8) = va1;
    *(bf16x8*)(Bs + tid * 8)        = vb0;
    *(bf16x8*)(Bs + 2048 + tid * 8) = vb1;
    __syncthreads();

    bf16x8 af[4], bfr[4];
#pragma unroll
    for (int i = 0; i < 4; ++i)
      af[i] = *(const bf16x8*)(As + (wm + i * 16 + l15) * 32 + quad * 8);
#pragma unroll
    for (int j = 0; j < 4; ++j)
      bfr[j] = *(const bf16x8*)(Bs + (wn + j * 16 + l15) * 32 + quad * 8);
#pragma unroll
    for (int i = 0; i < 4; ++i)
#pragma unroll
      for (int j = 0; j < 4; ++j)
        acc[i][j] = MFMA16(af[i], bfr[j], acc[i][j]);
  }

#pragma unroll
  for (int i = 0; i < 4; ++i) {
    const int m = m0 + wm + i * 16 + quad * 4;
#pragma unroll
    for (int j = 0; j < 4; ++j) {
      const int n = n0 + wn + j * 16 + l15;
#pragma unroll
      for (int r = 0; r < 4; ++r)
        C[(size_t)(m + r) * N + n] = acc[i][j][r];
    }
  }
}

// ---------------------------------------------------------------------------
extern "C" void kernel_launch(void* const* d_in, const int* in_sizes, int n_in,
                              void* d_out, int out_size, void* d_ws, size_t ws_size,
                              hipStream_t stream) {
  const float* x  = nullptr;   // 8388608 elems
  const float* wq = nullptr;   // 3145728
  const float* wp = nullptr;   // 1048576
  for (int i = 0; i < n_in; ++i) {
    if      (in_sizes[i] == 8388608) x  = (const float*)d_in[i];
    else if (in_sizes[i] == 3145728) wq = (const float*)d_in[i];
    else if (in_sizes[i] == 1048576) wp = (const float*)d_in[i];
  }
  if (!x || !wq || !wp) {
    x = (const float*)d_in[0]; wq = (const float*)d_in[1]; wp = (const float*)d_in[2];
  }

  float* out = (float*)d_out;            // [4,2048,1024] fp32, written once
  const size_t NE = (size_t)4 * 16 * 2048 * 64;  // 8388608
  bf16* kb = (bf16*)d_ws;                // base 64MB: K, V^T, Q, y
  bf16* vb = kb + NE;                    // V^T: [bh][64][2048]
  bf16* qb = vb + NE;
  bf16* yb = qb + NE;
  // extended region (bf16 copies of inputs)
  bf16* xb  = yb + NE;                   // 8388608 elems
  bf16* wqb = xb + 8388608;              // 3145728
  bf16* wpb = wqb + 3145728;             // 1048576
  const size_t need = (4 * NE + 8388608 + 3145728 + 1048576) * sizeof(bf16);
  const bool ext = ws_size >= need;      // deterministic -> graph-safe

  if (ext) {
    cvt_f32_bf16<<<(8388608 / 8 + 255) / 256, 256, 0, stream>>>(x, xb, 8388608 / 8);
    cvt_f32_bf16<<<(3145728 / 8 + 255) / 256, 256, 0, stream>>>(wq, wqb, 3145728 / 8);
    cvt_f32_bf16<<<(1048576 / 8 + 255) / 256, 256, 0, stream>>>(wp, wpb, 1048576 / 8);
    gemm_qkv_a<<<dim3(24, 64), 256, 0, stream>>>(xb, wqb, qb, kb, vb);
  } else {
    gemm_qkv_f<<<dim3(24, 64), 256, 0, stream>>>(x, wq, qb, kb, vb);
  }

  attn<<<dim3(16, 64), 256, 0, stream>>>(qb, kb, vb, yb);

  if (ext) {
    gemm_proj_a<<<dim3(8, 64), 256, 0, stream>>>(yb, wpb, out);
  } else {
    gemm_proj_f<<<dim3(8, 64), 256, 0, stream>>>(yb, wp, out);
  }
}

// Round 3
// 268.488 us; speedup vs baseline: 1.5857x; 1.5857x over previous
//
#include <hip/hip_runtime.h>
#include <cstdint>
#include <cstddef>

// Pipeline v7. B=4, T=2048, D=1024, H=16, HD=64. Inputs fp32, output fp32.
// attn v6: back to LDS double-buffered staging, but entirely via
// global_load_lds (async, compiler can't un-pipeline it) with pre-swizzled
// global source (linear LDS dest + XOR-involution source + swizzled read).
// V^T pre-transposed [bh][d][t] by QKV epilogue -> V staging is a plain async
// copy (v4's in-register V transpose VALU block is gone). 2-phase pipeline:
// STAGE(next) -> compute(cur) -> barrier. 40KB LDS, 4 blocks/CU.
// XCD-clustered remap; exp2-domain no-max softmax; s_setprio around MFMA.
// GEMMs unchanged (m97-style global_load_lds width-16 staging).

typedef __bf16 bf16;
typedef __bf16 bf16x4 __attribute__((ext_vector_type(4)));
typedef __bf16 bf16x8 __attribute__((ext_vector_type(8)));
typedef float  f32x4  __attribute__((ext_vector_type(4)));
typedef float  fvec4  __attribute__((ext_vector_type(4)));

typedef __attribute__((address_space(1))) const void global_cv;
typedef __attribute__((address_space(3))) void lds_v;

#define MFMA16(a, b, c) __builtin_amdgcn_mfma_f32_16x16x32_bf16((a), (b), (c), 0, 0, 0)

// Q scale: 1/sqrt(64) * log2(e)  (softmax done in exp2 domain)
#define QSCALE 0.18033688f

__device__ __forceinline__ void async_ld16(const bf16* g, bf16* l) {
  // gfx950 16B direct global->LDS; dest = wave-uniform base + lane*16.
  __builtin_amdgcn_global_load_lds((global_cv*)g, (lds_v*)l, 16, 0, 0);
}

// XOR chunk swizzle for [rows][64] bf16 LDS tiles.
__device__ __forceinline__ int swz_off(int row, int col) {
  int sr = (row & 7) ^ ((row >> 3) & 7);
  return row * 64 + ((((col >> 3) ^ sr) & 7) * 8) + (col & 7);
}

__device__ __forceinline__ bf16x8 cvt8(const float* p) {
  fvec4 u = *(const fvec4*)p;
  fvec4 v = *(const fvec4*)(p + 4);
  bf16x8 r;
  r[0] = (bf16)u[0]; r[1] = (bf16)u[1]; r[2] = (bf16)u[2]; r[3] = (bf16)u[3];
  r[4] = (bf16)v[0]; r[5] = (bf16)v[1]; r[6] = (bf16)v[2]; r[7] = (bf16)v[3];
  return r;
}

// ---------------------------------------------------------------------------
// fp32 -> bf16 bulk convert (8 elems/thread).
// ---------------------------------------------------------------------------
__global__ void cvt_f32_bf16(const float* __restrict__ s, bf16* __restrict__ d,
                             int n8) {
  int i = blockIdx.x * 256 + threadIdx.x;
  if (i < n8) *(bf16x8*)(d + (size_t)i * 8) = cvt8(s + (size_t)i * 8);
}

// ---------------------------------------------------------------------------
// Shared epilogue: Q,K as [bh][t][64]; V TRANSPOSED as [bh][d][t].
// ---------------------------------------------------------------------------
__device__ __forceinline__ void qkv_scatter(const f32x4 acc[4][4], int m0, int n0,
                                            int wm, int wn, int quad, int l15,
                                            bf16* Qo, bf16* Ko, bf16* Vo) {
  const int which = n0 >> 10;  // 0=Q 1=K 2=V
  if (which == 2) {
    // V^T: [bh][d][t]; 4 accumulator rows per lane are t-consecutive -> 8B store
#pragma unroll
    for (int i = 0; i < 4; ++i) {
      const int m = m0 + wm + i * 16 + quad * 4;  // multiple of 4, no b-crossing
      const int b = m >> 11;
      const int t = m & 2047;
#pragma unroll
      for (int j = 0; j < 4; ++j) {
        const int n1 = (n0 + wn + j * 16 + l15) & 1023;
        const int h  = n1 >> 6;
        const int d  = n1 & 63;
        bf16x4 v;
#pragma unroll
        for (int r = 0; r < 4; ++r) v[r] = (bf16)acc[i][j][r];
        *(bf16x4*)(Vo + ((size_t)(b * 16 + h) * 64 + d) * 2048 + t) = v;
      }
    }
    return;
  }
  bf16* dst = (which == 0) ? Qo : Ko;
  const float scale = (which == 0) ? QSCALE : 1.0f;
#pragma unroll
  for (int i = 0; i < 4; ++i) {
    const int m = m0 + wm + i * 16 + quad * 4;
#pragma unroll
    for (int j = 0; j < 4; ++j) {
      const int n  = n0 + wn + j * 16 + l15;
      const int n1 = n & 1023;
      const int h  = n1 >> 6;
      const int d  = n1 & 63;
#pragma unroll
      for (int r = 0; r < 4; ++r) {
        const int mm = m + r;
        const int b  = mm >> 11;
        const int t  = mm & 2047;
        dst[(((size_t)(b * 16 + h)) * 2048 + t) * 64 + d] =
            (bf16)(acc[i][j][r] * scale);
      }
    }
  }
}

// ---------------------------------------------------------------------------
// QKV GEMM, bf16 async-staging variant (plan A). grid (24,64).
// ---------------------------------------------------------------------------
__global__ __launch_bounds__(256, 2)
void gemm_qkv_a(const bf16* __restrict__ A, const bf16* __restrict__ B,
                bf16* __restrict__ Qo, bf16* __restrict__ Ko,
                bf16* __restrict__ Vo) {
  __shared__ __align__(16) bf16 As[128 * 32];
  __shared__ __align__(16) bf16 Bs[128 * 32];
  const int K = 1024;

  const int tid  = threadIdx.x;
  const int lane = tid & 63;
  const int wave = tid >> 6;
  const int quad = lane >> 4;
  const int l15  = lane & 15;
  const int wm   = (wave >> 1) * 64;
  const int wn   = (wave & 1) * 64;
  const int m0   = blockIdx.y * 128;
  const int n0   = blockIdx.x * 128;

  f32x4 acc[4][4];
#pragma unroll
  for (int i = 0; i < 4; ++i)
#pragma unroll
    for (int j = 0; j < 4; ++j) acc[i][j] = f32x4{0.f, 0.f, 0.f, 0.f};

  const int r0 = tid >> 2;
  const int c0 = (tid & 3) * 8;
  const bf16* ag0 = A + (size_t)(m0 + r0) * K + c0;
  const bf16* ag1 = A + (size_t)(m0 + 64 + r0) * K + c0;
  const bf16* bg0 = B + (size_t)(n0 + r0) * K + c0;
  const bf16* bg1 = B + (size_t)(n0 + 64 + r0) * K + c0;
  const int lo0 = (wave * 64) * 8;        // wave-uniform LDS elem offset
  const int lo1 = (256 + wave * 64) * 8;

  for (int k0 = 0; k0 < K; k0 += 32) {
    __syncthreads();
    async_ld16(ag0 + k0, As + lo0);
    async_ld16(ag1 + k0, As + lo1);
    async_ld16(bg0 + k0, Bs + lo0);
    async_ld16(bg1 + k0, Bs + lo1);
    __syncthreads();

    bf16x8 af[4], bfr[4];
#pragma unroll
    for (int i = 0; i < 4; ++i)
      af[i] = *(const bf16x8*)(As + (wm + i * 16 + l15) * 32 + quad * 8);
#pragma unroll
    for (int j = 0; j < 4; ++j)
      bfr[j] = *(const bf16x8*)(Bs + (wn + j * 16 + l15) * 32 + quad * 8);
#pragma unroll
    for (int i = 0; i < 4; ++i)
#pragma unroll
      for (int j = 0; j < 4; ++j)
        acc[i][j] = MFMA16(af[i], bfr[j], acc[i][j]);
  }
  qkv_scatter(acc, m0, n0, wm, wn, quad, l15, Qo, Ko, Vo);
}

// ---------------------------------------------------------------------------
// QKV GEMM, fp32 cvt8 register-staging variant (plan B fallback). grid (24,64).
// ---------------------------------------------------------------------------
__global__ __launch_bounds__(256, 2)
void gemm_qkv_f(const float* __restrict__ A, const float* __restrict__ B,
                bf16* __restrict__ Qo, bf16* __restrict__ Ko,
                bf16* __restrict__ Vo) {
  __shared__ __align__(16) bf16 As[128 * 32];
  __shared__ __align__(16) bf16 Bs[128 * 32];
  const int K = 1024;

  const int tid  = threadIdx.x;
  const int lane = tid & 63;
  const int wave = tid >> 6;
  const int quad = lane >> 4;
  const int l15  = lane & 15;
  const int wm   = (wave >> 1) * 64;
  const int wn   = (wave & 1) * 64;
  const int m0   = blockIdx.y * 128;
  const int n0   = blockIdx.x * 128;

  f32x4 acc[4][4];
#pragma unroll
  for (int i = 0; i < 4; ++i)
#pragma unroll
    for (int j = 0; j < 4; ++j) acc[i][j] = f32x4{0.f, 0.f, 0.f, 0.f};

  const int r0 = tid >> 2;
  const int c0 = (tid & 3) * 8;
  const size_t aoff0 = (size_t)(m0 + r0) * K + c0;
  const size_t aoff1 = (size_t)(m0 + 64 + r0) * K + c0;
  const size_t boff0 = (size_t)(n0 + r0) * K + c0;
  const size_t boff1 = (size_t)(n0 + 64 + r0) * K + c0;

  for (int k0 = 0; k0 < K; k0 += 32) {
    bf16x8 va0 = cvt8(A + aoff0 + k0);
    bf16x8 va1 = cvt8(A + aoff1 + k0);
    bf16x8 vb0 = cvt8(B + boff0 + k0);
    bf16x8 vb1 = cvt8(B + boff1 + k0);
    __syncthreads();
    *(bf16x8*)(As + tid * 8)        = va0;
    *(bf16x8*)(As + 2048 + tid * 8) = va1;
    *(bf16x8*)(Bs + tid * 8)        = vb0;
    *(bf16x8*)(Bs + 2048 + tid * 8) = vb1;
    __syncthreads();

    bf16x8 af[4], bfr[4];
#pragma unroll
    for (int i = 0; i < 4; ++i)
      af[i] = *(const bf16x8*)(As + (wm + i * 16 + l15) * 32 + quad * 8);
#pragma unroll
    for (int j = 0; j < 4; ++j)
      bfr[j] = *(const bf16x8*)(Bs + (wn + j * 16 + l15) * 32 + quad * 8);
#pragma unroll
    for (int i = 0; i < 4; ++i)
#pragma unroll
      for (int j = 0; j < 4; ++j)
        acc[i][j] = MFMA16(af[i], bfr[j], acc[i][j]);
  }
  qkv_scatter(acc, m0, n0, wm, wn, quad, l15, Qo, Ko, Vo);
}

// ---------------------------------------------------------------------------
// Flash attention v6, causal. grid (16,64) remapped so XCD c (= lin%8) owns
// heads 8c..8c+7; block handles q-tiles {p, 31-p} (33 kv-tiles, balanced).
// K and V^T tiles staged to LDS via global_load_lds (4 issues/wave/tile),
// double-buffered; 2-phase pipeline: STAGE(next) -> compute(cur) -> barrier.
// Source addresses pre-XOR-swizzled so linear LDS writes land at swizzled
// positions (read with swz_off). P strip per-wave. exp2-domain softmax.
// ---------------------------------------------------------------------------
__global__ __launch_bounds__(256, 4)
void attn(const bf16* __restrict__ Q, const bf16* __restrict__ Kk,
          const bf16* __restrict__ Vt, bf16* __restrict__ Y) {
  __shared__ __align__(16) bf16 Ks[2][64 * 64];   // [kv][d] swizzled
  __shared__ __align__(16) bf16 Vs[2][64 * 64];   // [d][kv] swizzled
  __shared__ __align__(16) bf16 Ps[4 * 16 * 64];  // per-wave P strips

  const int tid  = threadIdx.x;
  const int wave = tid >> 6;
  const int lane = tid & 63;
  const int quad = lane >> 4;
  const int l15  = lane & 15;

  // XCD-clustered remap: lin%8 = XCD; each XCD gets heads [8c, 8c+8).
  const int lin  = (int)blockIdx.x + ((int)blockIdx.y << 4);
  const int slot = lin >> 3;                 // 0..127 within XCD
  const int bh   = (lin & 7) * 8 + (slot >> 4);
  const int p    = slot & 15;
  const int b    = bh >> 4;
  const int h    = bh & 15;

  const bf16* Qb = Q  + (size_t)bh * (2048 * 64);
  const bf16* Kb = Kk + (size_t)bh * (2048 * 64);   // [t][64]
  const bf16* Vb = Vt + (size_t)bh * (2048 * 64);   // [64][2048] (transposed)
  bf16* Pw = Ps + wave * (16 * 64);

  // Staging lane constants. Issue i covers tile rows i*32 + wave*8 + (lane>>3);
  // lane chunk q = lane&7. Global source chunk is XOR'd with the row swizzle
  // (involution) so the linear LDS write lands at the swizzled position.
  const int r0s = wave * 8 + (lane >> 3);       // issue-0 row (0..31)
  const int r1s = r0s + 32;                     // issue-1 row (32..63)
  const int qch = lane & 7;
  const int co0 = (((qch ^ ((r0s & 7) ^ ((r0s >> 3) & 7)))) & 7) * 8;
  const int co1 = (((qch ^ ((r1s & 7) ^ ((r1s >> 3) & 7)))) & 7) * 8;
  const bf16* kg0 = Kb + (size_t)r0s * 64 + co0;    // + k0*64 per tile
  const bf16* kg1 = Kb + (size_t)r1s * 64 + co1;
  const bf16* vg0 = Vb + (size_t)r0s * 2048 + co0;  // + k0 per tile
  const bf16* vg1 = Vb + (size_t)r1s * 2048 + co1;
  const int ldsw = wave * 512;                  // wave-uniform elem offset

  const float NEG = -1e30f;

#pragma unroll 1
  for (int pass = 0; pass < 2; ++pass) {
    const int qt = pass ? (31 - p) : p;
    const int q0 = qt * 64;

    const bf16* qp = Qb + (size_t)(q0 + wave * 16 + l15) * 64 + quad * 8;
    bf16x8 qa0 = *(const bf16x8*)qp;
    bf16x8 qa1 = *(const bf16x8*)(qp + 32);

    f32x4 l_run = {0.f, 0.f, 0.f, 0.f};
    f32x4 o[4];
#pragma unroll
    for (int j = 0; j < 4; ++j) o[j] = f32x4{0.f, 0.f, 0.f, 0.f};

    // prologue: stage kv-tile 0 into buffer 0
    async_ld16(kg0, Ks[0] + ldsw);
    async_ld16(kg1, Ks[0] + 2048 + ldsw);
    async_ld16(vg0, Vs[0] + ldsw);
    async_ld16(vg1, Vs[0] + 2048 + ldsw);
    __syncthreads();

#pragma unroll 1
    for (int kt = 0; kt <= qt; ++kt) {
      const int cur = kt & 1;
      const int k0  = kt * 64;

      // stage NEXT tile into the other buffer (async; drains at the barrier)
      if (kt < qt) {
        const int kn = k0 + 64;
        async_ld16(kg0 + (size_t)kn * 64, Ks[cur ^ 1] + ldsw);
        async_ld16(kg1 + (size_t)kn * 64, Ks[cur ^ 1] + 2048 + ldsw);
        async_ld16(vg0 + kn, Vs[cur ^ 1] + ldsw);
        async_ld16(vg1 + kn, Vs[cur ^ 1] + 2048 + ldsw);
      }

      // S = Q K^T (log2 domain via QSCALE)
      f32x4 s[4];
      __builtin_amdgcn_s_setprio(1);
#pragma unroll
      for (int j = 0; j < 4; ++j) {
        const int kvr = j * 16 + l15;
        bf16x8 k0f = *(const bf16x8*)(Ks[cur] + swz_off(kvr, quad * 8));
        bf16x8 k1f = *(const bf16x8*)(Ks[cur] + swz_off(kvr, 32 + quad * 8));
        f32x4 z = {0.f, 0.f, 0.f, 0.f};
        z = MFMA16(qa0, k0f, z);
        z = MFMA16(qa1, k1f, z);
        s[j] = z;
      }
      __builtin_amdgcn_s_setprio(0);

      if (kt == qt) {  // diagonal: causal mask
#pragma unroll
        for (int j = 0; j < 4; ++j) {
          const int kvg = k0 + j * 16 + l15;
#pragma unroll
          for (int r = 0; r < 4; ++r) {
            const int qg = q0 + wave * 16 + quad * 4 + r;
            if (kvg > qg) s[j][r] = NEG;
          }
        }
      }

      // p = exp2(s); accumulate per-lane l partials
#pragma unroll
      for (int j = 0; j < 4; ++j)
#pragma unroll
        for (int r = 0; r < 4; ++r) {
          float pv = exp2f(s[j][r]);
          s[j][r] = pv;
          l_run[r] += pv;
        }

      // P: C-layout -> per-wave LDS strip -> A-operand frags
#pragma unroll
      for (int j = 0; j < 4; ++j)
#pragma unroll
        for (int r = 0; r < 4; ++r)
          Pw[swz_off(quad * 4 + r, j * 16 + l15)] = (bf16)s[j][r];

      bf16x8 pf0 = *(const bf16x8*)(Pw + swz_off(l15, quad * 8));
      bf16x8 pf1 = *(const bf16x8*)(Pw + swz_off(l15, 32 + quad * 8));

      // PV from V^T tile
      __builtin_amdgcn_s_setprio(1);
#pragma unroll
      for (int j = 0; j < 4; ++j) {
        const int d = j * 16 + l15;
        bf16x8 vf0 = *(const bf16x8*)(Vs[cur] + swz_off(d, quad * 8));
        bf16x8 vf1 = *(const bf16x8*)(Vs[cur] + swz_off(d, 32 + quad * 8));
        o[j] = MFMA16(pf0, vf0, o[j]);
        o[j] = MFMA16(pf1, vf1, o[j]);
      }
      __builtin_amdgcn_s_setprio(0);

      __syncthreads();  // drains staging (vmcnt) + protects both buffers
    }

    // one deferred 16-lane reduce for l (lanes of a quad hold same rows)
#pragma unroll
    for (int msk = 1; msk < 16; msk <<= 1)
#pragma unroll
      for (int r = 0; r < 4; ++r) l_run[r] += __shfl_xor(l_run[r], msk);

    float inv[4];
#pragma unroll
    for (int r = 0; r < 4; ++r) inv[r] = 1.0f / l_run[r];

#pragma unroll
    for (int j = 0; j < 4; ++j) {
      const int dcol = h * 64 + j * 16 + l15;
#pragma unroll
      for (int r = 0; r < 4; ++r) {
        const int trow = q0 + wave * 16 + quad * 4 + r;
        Y[((size_t)b * 2048 + trow) * 1024 + dcol] = (bf16)(o[j][r] * inv[r]);
      }
    }
  }
}

// ---------------------------------------------------------------------------
// Projection GEMM, bf16 async variant (plan A): out fp32 = y(bf16)*wpb^T.
// grid (8,64).
// ---------------------------------------------------------------------------
__global__ __launch_bounds__(256, 2)
void gemm_proj_a(const bf16* __restrict__ A, const bf16* __restrict__ B,
                 float* __restrict__ C) {
  __shared__ __align__(16) bf16 As[128 * 32];
  __shared__ __align__(16) bf16 Bs[128 * 32];
  const int K = 1024, N = 1024;

  const int tid  = threadIdx.x;
  const int lane = tid & 63;
  const int wave = tid >> 6;
  const int quad = lane >> 4;
  const int l15  = lane & 15;
  const int wm   = (wave >> 1) * 64;
  const int wn   = (wave & 1) * 64;
  const int m0   = blockIdx.y * 128;
  const int n0   = blockIdx.x * 128;

  f32x4 acc[4][4];
#pragma unroll
  for (int i = 0; i < 4; ++i)
#pragma unroll
    for (int j = 0; j < 4; ++j) acc[i][j] = f32x4{0.f, 0.f, 0.f, 0.f};

  const int r0 = tid >> 2;
  const int c0 = (tid & 3) * 8;
  const bf16* ag0 = A + (size_t)(m0 + r0) * K + c0;
  const bf16* ag1 = A + (size_t)(m0 + 64 + r0) * K + c0;
  const bf16* bg0 = B + (size_t)(n0 + r0) * K + c0;
  const bf16* bg1 = B + (size_t)(n0 + 64 + r0) * K + c0;
  const int lo0 = (wave * 64) * 8;
  const int lo1 = (256 + wave * 64) * 8;

  for (int k0 = 0; k0 < K; k0 += 32) {
    __syncthreads();
    async_ld16(ag0 + k0, As + lo0);
    async_ld16(ag1 + k0, As + lo1);
    async_ld16(bg0 + k0, Bs + lo0);
    async_ld16(bg1 + k0, Bs + lo1);
    __syncthreads();

    bf16x8 af[4], bfr[4];
#pragma unroll
    for (int i = 0; i < 4; ++i)
      af[i] = *(const bf16x8*)(As + (wm + i * 16 + l15) * 32 + quad * 8);
#pragma unroll
    for (int j = 0; j < 4; ++j)
      bfr[j] = *(const bf16x8*)(Bs + (wn + j * 16 + l15) * 32 + quad * 8);
#pragma unroll
    for (int i = 0; i < 4; ++i)
#pragma unroll
      for (int j = 0; j < 4; ++j)
        acc[i][j] = MFMA16(af[i], bfr[j], acc[i][j]);
  }

#pragma unroll
  for (int i = 0; i < 4; ++i) {
    const int m = m0 + wm + i * 16 + quad * 4;
#pragma unroll
    for (int j = 0; j < 4; ++j) {
      const int n = n0 + wn + j * 16 + l15;
#pragma unroll
      for (int r = 0; r < 4; ++r)
        C[(size_t)(m + r) * N + n] = acc[i][j][r];
    }
  }
}

// ---------------------------------------------------------------------------
// Projection GEMM, fp32-B fallback (plan B). grid (8,64).
// ---------------------------------------------------------------------------
__global__ __launch_bounds__(256, 2)
void gemm_proj_f(const bf16* __restrict__ A, const float* __restrict__ B,
                 float* __restrict__ C) {
  __shared__ __align__(16) bf16 As[128 * 32];
  __shared__ __align__(16) bf16 Bs[128 * 32];
  const int K = 1024, N = 1024;

  const int tid  = threadIdx.x;
  const int lane = tid & 63;
  const int wave = tid >> 6;
  const int quad = lane >> 4;
  const int l15  = lane & 15;
  const int wm   = (wave >> 1) * 64;
  const int wn   = (wave & 1) * 64;
  const int m0   = blockIdx.y * 128;
  const int n0   = blockIdx.x * 128;

  f32x4 acc[4][4];
#pragma unroll
  for (int i = 0; i < 4; ++i)
#pragma unroll
    for (int j = 0; j < 4; ++j) acc[i][j] = f32x4{0.f, 0.f, 0.f, 0.f};

  const int r0 = tid >> 2;
  const int c0 = (tid & 3) * 8;
  const size_t aoff0 = (size_t)(m0 + r0) * K + c0;
  const size_t aoff1 = (size_t)(m0 + 64 + r0) * K + c0;
  const size_t boff0 = (size_t)(n0 + r0) * K + c0;
  const size_t boff1 = (size_t)(n0 + 64 + r0) * K + c0;

  for (int k0 = 0; k0 < K; k0 += 32) {
    bf16x8 va0 = *(const bf16x8*)(A + aoff0 + k0);
    bf16x8 va1 = *(const bf16x8*)(A + aoff1 + k0);
    bf16x8 vb0 = cvt8(B + boff0 + k0);
    bf16x8 vb1 = cvt8(B + boff1 + k0);
    __syncthreads();
    *(bf16x8*)(As + tid * 8)        = va0;
    *(bf16x8*)(As + 2048 + tid * 8) = va1;
    *(bf16x8*)(Bs + tid * 8)        = vb0;
    *(bf16x8*)(Bs + 2048 + tid * 8) = vb1;
    __syncthreads();

    bf16x8 af[4], bfr[4];
#pragma unroll
    for (int i = 0; i < 4; ++i)
      af[i] = *(const bf16x8*)(As + (wm + i * 16 + l15) * 32 + quad * 8);
#pragma unroll
    for (int j = 0; j < 4; ++j)
      bfr[j] = *(const bf16x8*)(Bs + (wn + j * 16 + l15) * 32 + quad * 8);
#pragma unroll
    for (int i = 0; i < 4; ++i)
#pragma unroll
      for (int j = 0; j < 4; ++j)
        acc[i][j] = MFMA16(af[i], bfr[j], acc[i][j]);
  }

#pragma unroll
  for (int i = 0; i < 4; ++i) {
    const int m = m0 + wm + i * 16 + quad * 4;
#pragma unroll
    for (int j = 0; j < 4; ++j) {
      const int n = n0 + wn + j * 16 + l15;
#pragma unroll
      for (int r = 0; r < 4; ++r)
        C[(size_t)(m + r) * N + n] = acc[i][j][r];
    }
  }
}

// ---------------------------------------------------------------------------
extern "C" void kernel_launch(void* const* d_in, const int* in_sizes, int n_in,
                              void* d_out, int out_size, void* d_ws, size_t ws_size,
                              hipStream_t stream) {
  const float* x  = nullptr;   // 8388608 elems
  const float* wq = nullptr;   // 3145728
  const float* wp = nullptr;   // 1048576
  for (int i = 0; i < n_in; ++i) {
    if      (in_sizes[i] == 8388608) x  = (const float*)d_in[i];
    else if (in_sizes[i] == 3145728) wq = (const float*)d_in[i];
    else if (in_sizes[i] == 1048576) wp = (const float*)d_in[i];
  }
  if (!x || !wq || !wp) {
    x = (const float*)d_in[0]; wq = (const float*)d_in[1]; wp = (const float*)d_in[2];
  }

  float* out = (float*)d_out;            // [4,2048,1024] fp32, written once
  const size_t NE = (size_t)4 * 16 * 2048 * 64;  // 8388608
  bf16* kb = (bf16*)d_ws;                // base 64MB: K, V^T, Q, y
  bf16* vb = kb + NE;                    // V^T: [bh][64][2048]
  bf16* qb = vb + NE;
  bf16* yb = qb + NE;
  // extended region (bf16 copies of inputs)
  bf16* xb  = yb + NE;                   // 8388608 elems
  bf16* wqb = xb + 8388608;              // 3145728
  bf16* wpb = wqb + 3145728;             // 1048576
  const size_t need = (4 * NE + 8388608 + 3145728 + 1048576) * sizeof(bf16);
  const bool ext = ws_size >= need;      // deterministic -> graph-safe

  if (ext) {
    cvt_f32_bf16<<<(8388608 / 8 + 255) / 256, 256, 0, stream>>>(x, xb, 8388608 / 8);
    cvt_f32_bf16<<<(3145728 / 8 + 255) / 256, 256, 0, stream>>>(wq, wqb, 3145728 / 8);
    cvt_f32_bf16<<<(1048576 / 8 + 255) / 256, 256, 0, stream>>>(wp, wpb, 1048576 / 8);
    gemm_qkv_a<<<dim3(24, 64), 256, 0, stream>>>(xb, wqb, qb, kb, vb);
  } else {
    gemm_qkv_f<<<dim3(24, 64), 256, 0, stream>>>(x, wq, qb, kb, vb);
  }

  attn<<<dim3(16, 64), 256, 0, stream>>>(qb, kb, vb, yb);

  if (ext) {
    gemm_proj_a<<<dim3(8, 64), 256, 0, stream>>>(yb, wpb, out);
  } else {
    gemm_proj_f<<<dim3(8, 64), 256, 0, stream>>>(yb, wp, out);
  }
}

// Round 4
// 264.466 us; speedup vs baseline: 1.6098x; 1.0152x over previous
//
#include <hip/hip_runtime.h>
#include <cstdint>
#include <cstddef>

// Pipeline v8. B=4, T=2048, D=1024, H=16, HD=64. Inputs fp32, output fp32.
// attn v7: swapped QK^T (MFMA(K,Q) -> S^T) makes each lane hold 4 consecutive
// k-values of ONE q-row per j-block. P path becomes 8 cvt_pk + 4 ds_write_b64
// (16B-chunk XOR swizzle, conflict-free) instead of 16 cvt + 16 ds_write_u16
// (the 9.7M-conflict source). l is a lane-scalar; 2 shfl_xor + 4 shfl reduce.
// Rest unchanged from v7: global_load_lds double-buffered K/V staging with
// pre-swizzled source, V^T precomputed [bh][d][t], XCD-clustered remap,
// exp2-domain no-max softmax, s_setprio around MFMA clusters.
// GEMMs unchanged (m97-style global_load_lds width-16 staging).

typedef __bf16 bf16;
typedef __bf16 bf16x4 __attribute__((ext_vector_type(4)));
typedef __bf16 bf16x8 __attribute__((ext_vector_type(8)));
typedef float  f32x4  __attribute__((ext_vector_type(4)));
typedef float  fvec4  __attribute__((ext_vector_type(4)));
typedef unsigned u32x2 __attribute__((ext_vector_type(2)));

typedef __attribute__((address_space(1))) const void global_cv;
typedef __attribute__((address_space(3))) void lds_v;

#define MFMA16(a, b, c) __builtin_amdgcn_mfma_f32_16x16x32_bf16((a), (b), (c), 0, 0, 0)

// Q scale: 1/sqrt(64) * log2(e)  (softmax done in exp2 domain)
#define QSCALE 0.18033688f

__device__ __forceinline__ void async_ld16(const bf16* g, bf16* l) {
  // gfx950 16B direct global->LDS; dest = wave-uniform base + lane*16.
  __builtin_amdgcn_global_load_lds((global_cv*)g, (lds_v*)l, 16, 0, 0);
}

// XOR chunk swizzle for [rows][64] bf16 LDS tiles (K/V staging + frag reads).
__device__ __forceinline__ int swz_off(int row, int col) {
  int sr = (row & 7) ^ ((row >> 3) & 7);
  return row * 64 + ((((col >> 3) ^ sr) & 7) * 8) + (col & 7);
}

// packed f32x2 -> bf16x2 (no builtin on gfx950; T12 recipe)
__device__ __forceinline__ unsigned cvt_pk(float lo, float hi) {
  unsigned r;
  asm("v_cvt_pk_bf16_f32 %0, %1, %2" : "=v"(r) : "v"(lo), "v"(hi));
  return r;
}

__device__ __forceinline__ bf16x8 cvt8(const float* p) {
  fvec4 u = *(const fvec4*)p;
  fvec4 v = *(const fvec4*)(p + 4);
  bf16x8 r;
  r[0] = (bf16)u[0]; r[1] = (bf16)u[1]; r[2] = (bf16)u[2]; r[3] = (bf16)u[3];
  r[4] = (bf16)v[0]; r[5] = (bf16)v[1]; r[6] = (bf16)v[2]; r[7] = (bf16)v[3];
  return r;
}

// ---------------------------------------------------------------------------
// fp32 -> bf16 bulk convert (8 elems/thread).
// ---------------------------------------------------------------------------
__global__ void cvt_f32_bf16(const float* __restrict__ s, bf16* __restrict__ d,
                             int n8) {
  int i = blockIdx.x * 256 + threadIdx.x;
  if (i < n8) *(bf16x8*)(d + (size_t)i * 8) = cvt8(s + (size_t)i * 8);
}

// ---------------------------------------------------------------------------
// Shared epilogue: Q,K as [bh][t][64]; V TRANSPOSED as [bh][d][t].
// ---------------------------------------------------------------------------
__device__ __forceinline__ void qkv_scatter(const f32x4 acc[4][4], int m0, int n0,
                                            int wm, int wn, int quad, int l15,
                                            bf16* Qo, bf16* Ko, bf16* Vo) {
  const int which = n0 >> 10;  // 0=Q 1=K 2=V
  if (which == 2) {
    // V^T: [bh][d][t]; 4 accumulator rows per lane are t-consecutive -> 8B store
#pragma unroll
    for (int i = 0; i < 4; ++i) {
      const int m = m0 + wm + i * 16 + quad * 4;  // multiple of 4, no b-crossing
      const int b = m >> 11;
      const int t = m & 2047;
#pragma unroll
      for (int j = 0; j < 4; ++j) {
        const int n1 = (n0 + wn + j * 16 + l15) & 1023;
        const int h  = n1 >> 6;
        const int d  = n1 & 63;
        bf16x4 v;
#pragma unroll
        for (int r = 0; r < 4; ++r) v[r] = (bf16)acc[i][j][r];
        *(bf16x4*)(Vo + ((size_t)(b * 16 + h) * 64 + d) * 2048 + t) = v;
      }
    }
    return;
  }
  bf16* dst = (which == 0) ? Qo : Ko;
  const float scale = (which == 0) ? QSCALE : 1.0f;
#pragma unroll
  for (int i = 0; i < 4; ++i) {
    const int m = m0 + wm + i * 16 + quad * 4;
#pragma unroll
    for (int j = 0; j < 4; ++j) {
      const int n  = n0 + wn + j * 16 + l15;
      const int n1 = n & 1023;
      const int h  = n1 >> 6;
      const int d  = n1 & 63;
#pragma unroll
      for (int r = 0; r < 4; ++r) {
        const int mm = m + r;
        const int b  = mm >> 11;
        const int t  = mm & 2047;
        dst[(((size_t)(b * 16 + h)) * 2048 + t) * 64 + d] =
            (bf16)(acc[i][j][r] * scale);
      }
    }
  }
}

// ---------------------------------------------------------------------------
// QKV GEMM, bf16 async-staging variant (plan A). grid (24,64).
// ---------------------------------------------------------------------------
__global__ __launch_bounds__(256, 2)
void gemm_qkv_a(const bf16* __restrict__ A, const bf16* __restrict__ B,
                bf16* __restrict__ Qo, bf16* __restrict__ Ko,
                bf16* __restrict__ Vo) {
  __shared__ __align__(16) bf16 As[128 * 32];
  __shared__ __align__(16) bf16 Bs[128 * 32];
  const int K = 1024;

  const int tid  = threadIdx.x;
  const int lane = tid & 63;
  const int wave = tid >> 6;
  const int quad = lane >> 4;
  const int l15  = lane & 15;
  const int wm   = (wave >> 1) * 64;
  const int wn   = (wave & 1) * 64;
  const int m0   = blockIdx.y * 128;
  const int n0   = blockIdx.x * 128;

  f32x4 acc[4][4];
#pragma unroll
  for (int i = 0; i < 4; ++i)
#pragma unroll
    for (int j = 0; j < 4; ++j) acc[i][j] = f32x4{0.f, 0.f, 0.f, 0.f};

  const int r0 = tid >> 2;
  const int c0 = (tid & 3) * 8;
  const bf16* ag0 = A + (size_t)(m0 + r0) * K + c0;
  const bf16* ag1 = A + (size_t)(m0 + 64 + r0) * K + c0;
  const bf16* bg0 = B + (size_t)(n0 + r0) * K + c0;
  const bf16* bg1 = B + (size_t)(n0 + 64 + r0) * K + c0;
  const int lo0 = (wave * 64) * 8;        // wave-uniform LDS elem offset
  const int lo1 = (256 + wave * 64) * 8;

  for (int k0 = 0; k0 < K; k0 += 32) {
    __syncthreads();
    async_ld16(ag0 + k0, As + lo0);
    async_ld16(ag1 + k0, As + lo1);
    async_ld16(bg0 + k0, Bs + lo0);
    async_ld16(bg1 + k0, Bs + lo1);
    __syncthreads();

    bf16x8 af[4], bfr[4];
#pragma unroll
    for (int i = 0; i < 4; ++i)
      af[i] = *(const bf16x8*)(As + (wm + i * 16 + l15) * 32 + quad * 8);
#pragma unroll
    for (int j = 0; j < 4; ++j)
      bfr[j] = *(const bf16x8*)(Bs + (wn + j * 16 + l15) * 32 + quad * 8);
#pragma unroll
    for (int i = 0; i < 4; ++i)
#pragma unroll
      for (int j = 0; j < 4; ++j)
        acc[i][j] = MFMA16(af[i], bfr[j], acc[i][j]);
  }
  qkv_scatter(acc, m0, n0, wm, wn, quad, l15, Qo, Ko, Vo);
}

// ---------------------------------------------------------------------------
// QKV GEMM, fp32 cvt8 register-staging variant (plan B fallback). grid (24,64).
// ---------------------------------------------------------------------------
__global__ __launch_bounds__(256, 2)
void gemm_qkv_f(const float* __restrict__ A, const float* __restrict__ B,
                bf16* __restrict__ Qo, bf16* __restrict__ Ko,
                bf16* __restrict__ Vo) {
  __shared__ __align__(16) bf16 As[128 * 32];
  __shared__ __align__(16) bf16 Bs[128 * 32];
  const int K = 1024;

  const int tid  = threadIdx.x;
  const int lane = tid & 63;
  const int wave = tid >> 6;
  const int quad = lane >> 4;
  const int l15  = lane & 15;
  const int wm   = (wave >> 1) * 64;
  const int wn   = (wave & 1) * 64;
  const int m0   = blockIdx.y * 128;
  const int n0   = blockIdx.x * 128;

  f32x4 acc[4][4];
#pragma unroll
  for (int i = 0; i < 4; ++i)
#pragma unroll
    for (int j = 0; j < 4; ++j) acc[i][j] = f32x4{0.f, 0.f, 0.f, 0.f};

  const int r0 = tid >> 2;
  const int c0 = (tid & 3) * 8;
  const size_t aoff0 = (size_t)(m0 + r0) * K + c0;
  const size_t aoff1 = (size_t)(m0 + 64 + r0) * K + c0;
  const size_t boff0 = (size_t)(n0 + r0) * K + c0;
  const size_t boff1 = (size_t)(n0 + 64 + r0) * K + c0;

  for (int k0 = 0; k0 < K; k0 += 32) {
    bf16x8 va0 = cvt8(A + aoff0 + k0);
    bf16x8 va1 = cvt8(A + aoff1 + k0);
    bf16x8 vb0 = cvt8(B + boff0 + k0);
    bf16x8 vb1 = cvt8(B + boff1 + k0);
    __syncthreads();
    *(bf16x8*)(As + tid * 8)        = va0;
    *(bf16x8*)(As + 2048 + tid * 8) = va1;
    *(bf16x8*)(Bs + tid * 8)        = vb0;
    *(bf16x8*)(Bs + 2048 + tid * 8) = vb1;
    __syncthreads();

    bf16x8 af[4], bfr[4];
#pragma unroll
    for (int i = 0; i < 4; ++i)
      af[i] = *(const bf16x8*)(As + (wm + i * 16 + l15) * 32 + quad * 8);
#pragma unroll
    for (int j = 0; j < 4; ++j)
      bfr[j] = *(const bf16x8*)(Bs + (wn + j * 16 + l15) * 32 + quad * 8);
#pragma unroll
    for (int i = 0; i < 4; ++i)
#pragma unroll
      for (int j = 0; j < 4; ++j)
        acc[i][j] = MFMA16(af[i], bfr[j], acc[i][j]);
  }
  qkv_scatter(acc, m0, n0, wm, wn, quad, l15, Qo, Ko, Vo);
}

// ---------------------------------------------------------------------------
// Flash attention v7, causal. grid (16,64), XCD-clustered remap; block handles
// q-tiles {p, 31-p} (33 kv-tiles). Double-buffered global_load_lds staging.
// Swapped QK^T: s[j] = S^T fragment -> lane (l15,quad) holds P[q=l15] at
// k = 16j+4*quad+r (4 consecutive ks per j). P strip written as packed
// ds_write_b64 with 16B-chunk XOR swizzle (C ^= l15&7), read back as b128
// A-fragments for PV. l is a lane scalar; quad-reduce at the end.
// ---------------------------------------------------------------------------
__global__ __launch_bounds__(256, 4)
void attn(const bf16* __restrict__ Q, const bf16* __restrict__ Kk,
          const bf16* __restrict__ Vt, bf16* __restrict__ Y) {
  __shared__ __align__(16) bf16 Ks[2][64 * 64];   // [kv][d] swizzled
  __shared__ __align__(16) bf16 Vs[2][64 * 64];   // [d][kv] swizzled
  __shared__ __align__(16) bf16 Ps[4 * 16 * 64];  // per-wave P strips

  const int tid  = threadIdx.x;
  const int wave = tid >> 6;
  const int lane = tid & 63;
  const int quad = lane >> 4;
  const int l15  = lane & 15;

  // XCD-clustered remap: lin%8 = XCD; each XCD gets heads [8c, 8c+8).
  const int lin  = (int)blockIdx.x + ((int)blockIdx.y << 4);
  const int slot = lin >> 3;                 // 0..127 within XCD
  const int bh   = (lin & 7) * 8 + (slot >> 4);
  const int p    = slot & 15;
  const int b    = bh >> 4;
  const int h    = bh & 15;

  const bf16* Qb = Q  + (size_t)bh * (2048 * 64);
  const bf16* Kb = Kk + (size_t)bh * (2048 * 64);   // [t][64]
  const bf16* Vb = Vt + (size_t)bh * (2048 * 64);   // [64][2048] (transposed)
  char* Pw = (char*)(Ps + wave * (16 * 64));        // 2KB per-wave strip

  // Staging lane constants. Issue i covers tile rows i*32 + wave*8 + (lane>>3);
  // lane chunk q = lane&7. Global source chunk is XOR'd with the row swizzle
  // (involution) so the linear LDS write lands at the swizzled position.
  const int r0s = wave * 8 + (lane >> 3);       // issue-0 row (0..31)
  const int r1s = r0s + 32;                     // issue-1 row (32..63)
  const int qch = lane & 7;
  const int co0 = (((qch ^ ((r0s & 7) ^ ((r0s >> 3) & 7)))) & 7) * 8;
  const int co1 = (((qch ^ ((r1s & 7) ^ ((r1s >> 3) & 7)))) & 7) * 8;
  const bf16* kg0 = Kb + (size_t)r0s * 64 + co0;    // + k0*64 per tile
  const bf16* kg1 = Kb + (size_t)r1s * 64 + co1;
  const bf16* vg0 = Vb + (size_t)r0s * 2048 + co0;  // + k0 per tile
  const bf16* vg1 = Vb + (size_t)r1s * 2048 + co1;
  const int ldsw = wave * 512;                  // wave-uniform elem offset

  // P strip addressing (bytes): row = l15 (128B), 16B chunk C ^= (l15&7).
  const int psx   = l15 & 7;
  const int prowb = l15 * 128;
  const int pr0   = prowb + ((quad ^ psx) << 4);        // PV A-frag k 0..31
  const int pr1   = prowb + (((4 + quad) ^ psx) << 4);  // PV A-frag k 32..63

  const float NEG = -1e30f;

#pragma unroll 1
  for (int pass = 0; pass < 2; ++pass) {
    const int qt = pass ? (31 - p) : p;
    const int q0 = qt * 64;

    const bf16* qp = Qb + (size_t)(q0 + wave * 16 + l15) * 64 + quad * 8;
    bf16x8 qa0 = *(const bf16x8*)qp;
    bf16x8 qa1 = *(const bf16x8*)(qp + 32);

    f32x4 l4 = {0.f, 0.f, 0.f, 0.f};
    f32x4 o[4];
#pragma unroll
    for (int j = 0; j < 4; ++j) o[j] = f32x4{0.f, 0.f, 0.f, 0.f};

    // prologue: stage kv-tile 0 into buffer 0
    async_ld16(kg0, Ks[0] + ldsw);
    async_ld16(kg1, Ks[0] + 2048 + ldsw);
    async_ld16(vg0, Vs[0] + ldsw);
    async_ld16(vg1, Vs[0] + 2048 + ldsw);
    __syncthreads();

#pragma unroll 1
    for (int kt = 0; kt <= qt; ++kt) {
      const int cur = kt & 1;
      const int k0  = kt * 64;

      // stage NEXT tile into the other buffer (async; drains at the barrier)
      if (kt < qt) {
        const int kn = k0 + 64;
        async_ld16(kg0 + (size_t)kn * 64, Ks[cur ^ 1] + ldsw);
        async_ld16(kg1 + (size_t)kn * 64, Ks[cur ^ 1] + 2048 + ldsw);
        async_ld16(vg0 + kn, Vs[cur ^ 1] + ldsw);
        async_ld16(vg1 + kn, Vs[cur ^ 1] + 2048 + ldsw);
      }

      // S^T = K Q^T (log2 domain via QSCALE): lane -> q-row = l15,
      // k = k0 + 16j + 4*quad + r.
      f32x4 s[4];
      __builtin_amdgcn_s_setprio(1);
#pragma unroll
      for (int j = 0; j < 4; ++j) {
        const int kvr = j * 16 + l15;
        bf16x8 k0f = *(const bf16x8*)(Ks[cur] + swz_off(kvr, quad * 8));
        bf16x8 k1f = *(const bf16x8*)(Ks[cur] + swz_off(kvr, 32 + quad * 8));
        f32x4 z = {0.f, 0.f, 0.f, 0.f};
        z = MFMA16(k0f, qa0, z);   // swapped: A=K, B=Q -> C = S^T
        z = MFMA16(k1f, qa1, z);
        s[j] = z;
      }
      __builtin_amdgcn_s_setprio(0);

      if (kt == qt) {  // diagonal: causal mask (k_local > q_local)
        const int qloc = wave * 16 + l15;
#pragma unroll
        for (int j = 0; j < 4; ++j) {
#pragma unroll
          for (int r = 0; r < 4; ++r) {
            if (16 * j + 4 * quad + r > qloc) s[j][r] = NEG;
          }
        }
      }

      // p = exp2(s); vector-accumulate l partials (all same q-row = l15)
#pragma unroll
      for (int j = 0; j < 4; ++j) {
#pragma unroll
        for (int r = 0; r < 4; ++r) s[j][r] = exp2f(s[j][r]);
        l4 += s[j];
      }

      // P strip: 4 packed 8B writes (k = 16j+4*quad .. +3), chunk-swizzled.
#pragma unroll
      for (int j = 0; j < 4; ++j) {
        u32x2 pk;
        pk[0] = cvt_pk(s[j][0], s[j][1]);
        pk[1] = cvt_pk(s[j][2], s[j][3]);
        const int C = 2 * j + (quad >> 1);
        *(u32x2*)(Pw + prowb + (((C ^ psx) << 4) | ((quad & 1) << 3))) = pk;
      }

      bf16x8 pf0 = *(const bf16x8*)(Pw + pr0);
      bf16x8 pf1 = *(const bf16x8*)(Pw + pr1);

      // PV from V^T tile
      __builtin_amdgcn_s_setprio(1);
#pragma unroll
      for (int j = 0; j < 4; ++j) {
        const int d = j * 16 + l15;
        bf16x8 vf0 = *(const bf16x8*)(Vs[cur] + swz_off(d, quad * 8));
        bf16x8 vf1 = *(const bf16x8*)(Vs[cur] + swz_off(d, 32 + quad * 8));
        o[j] = MFMA16(pf0, vf0, o[j]);
        o[j] = MFMA16(pf1, vf1, o[j]);
      }
      __builtin_amdgcn_s_setprio(0);

      __syncthreads();  // drains staging (vmcnt) + protects both buffers
    }

    // l: fold 4 components (same q-row), reduce across quads, redistribute.
    float lf = (l4[0] + l4[1]) + (l4[2] + l4[3]);
    lf += __shfl_xor(lf, 16);
    lf += __shfl_xor(lf, 32);
    float inv[4];
#pragma unroll
    for (int r = 0; r < 4; ++r) inv[r] = 1.0f / __shfl(lf, quad * 4 + r);

#pragma unroll
    for (int j = 0; j < 4; ++j) {
      const int dcol = h * 64 + j * 16 + l15;
#pragma unroll
      for (int r = 0; r < 4; ++r) {
        const int trow = q0 + wave * 16 + quad * 4 + r;
        Y[((size_t)b * 2048 + trow) * 1024 + dcol] = (bf16)(o[j][r] * inv[r]);
      }
    }
  }
}

// ---------------------------------------------------------------------------
// Projection GEMM, bf16 async variant (plan A): out fp32 = y(bf16)*wpb^T.
// grid (8,64).
// ---------------------------------------------------------------------------
__global__ __launch_bounds__(256, 2)
void gemm_proj_a(const bf16* __restrict__ A, const bf16* __restrict__ B,
                 float* __restrict__ C) {
  __shared__ __align__(16) bf16 As[128 * 32];
  __shared__ __align__(16) bf16 Bs[128 * 32];
  const int K = 1024, N = 1024;

  const int tid  = threadIdx.x;
  const int lane = tid & 63;
  const int wave = tid >> 6;
  const int quad = lane >> 4;
  const int l15  = lane & 15;
  const int wm   = (wave >> 1) * 64;
  const int wn   = (wave & 1) * 64;
  const int m0   = blockIdx.y * 128;
  const int n0   = blockIdx.x * 128;

  f32x4 acc[4][4];
#pragma unroll
  for (int i = 0; i < 4; ++i)
#pragma unroll
    for (int j = 0; j < 4; ++j) acc[i][j] = f32x4{0.f, 0.f, 0.f, 0.f};

  const int r0 = tid >> 2;
  const int c0 = (tid & 3) * 8;
  const bf16* ag0 = A + (size_t)(m0 + r0) * K + c0;
  const bf16* ag1 = A + (size_t)(m0 + 64 + r0) * K + c0;
  const bf16* bg0 = B + (size_t)(n0 + r0) * K + c0;
  const bf16* bg1 = B + (size_t)(n0 + 64 + r0) * K + c0;
  const int lo0 = (wave * 64) * 8;
  const int lo1 = (256 + wave * 64) * 8;

  for (int k0 = 0; k0 < K; k0 += 32) {
    __syncthreads();
    async_ld16(ag0 + k0, As + lo0);
    async_ld16(ag1 + k0, As + lo1);
    async_ld16(bg0 + k0, Bs + lo0);
    async_ld16(bg1 + k0, Bs + lo1);
    __syncthreads();

    bf16x8 af[4], bfr[4];
#pragma unroll
    for (int i = 0; i < 4; ++i)
      af[i] = *(const bf16x8*)(As + (wm + i * 16 + l15) * 32 + quad * 8);
#pragma unroll
    for (int j = 0; j < 4; ++j)
      bfr[j] = *(const bf16x8*)(Bs + (wn + j * 16 + l15) * 32 + quad * 8);
#pragma unroll
    for (int i = 0; i < 4; ++i)
#pragma unroll
      for (int j = 0; j < 4; ++j)
        acc[i][j] = MFMA16(af[i], bfr[j], acc[i][j]);
  }

#pragma unroll
  for (int i = 0; i < 4; ++i) {
    const int m = m0 + wm + i * 16 + quad * 4;
#pragma unroll
    for (int j = 0; j < 4; ++j) {
      const int n = n0 + wn + j * 16 + l15;
#pragma unroll
      for (int r = 0; r < 4; ++r)
        C[(size_t)(m + r) * N + n] = acc[i][j][r];
    }
  }
}

// ---------------------------------------------------------------------------
// Projection GEMM, fp32-B fallback (plan B). grid (8,64).
// ---------------------------------------------------------------------------
__global__ __launch_bounds__(256, 2)
void gemm_proj_f(const bf16* __restrict__ A, const float* __restrict__ B,
                 float* __restrict__ C) {
  __shared__ __align__(16) bf16 As[128 * 32];
  __shared__ __align__(16) bf16 Bs[128 * 32];
  const int K = 1024, N = 1024;

  const int tid  = threadIdx.x;
  const int lane = tid & 63;
  const int wave = tid >> 6;
  const int quad = lane >> 4;
  const int l15  = lane & 15;
  const int wm   = (wave >> 1) * 64;
  const int wn   = (wave & 1) * 64;
  const int m0   = blockIdx.y * 128;
  const int n0   = blockIdx.x * 128;

  f32x4 acc[4][4];
#pragma unroll
  for (int i = 0; i < 4; ++i)
#pragma unroll
    for (int j = 0; j < 4; ++j) acc[i][j] = f32x4{0.f, 0.f, 0.f, 0.f};

  const int r0 = tid >> 2;
  const int c0 = (tid & 3) * 8;
  const size_t aoff0 = (size_t)(m0 + r0) * K + c0;
  const size_t aoff1 = (size_t)(m0 + 64 + r0) * K + c0;
  const size_t boff0 = (size_t)(n0 + r0) * K + c0;
  const size_t boff1 = (size_t)(n0 + 64 + r0) * K + c0;

  for (int k0 = 0; k0 < K; k0 += 32) {
    bf16x8 va0 = *(const bf16x8*)(A + aoff0 + k0);
    bf16x8 va1 = *(const bf16x8*)(A + aoff1 + k0);
    bf16x8 vb0 = cvt8(B + boff0 + k0);
    bf16x8 vb1 = cvt8(B + boff1 + k0);
    __syncthreads();
    *(bf16x8*)(As + tid * 8)        = va0;
    *(bf16x8*)(As + 2048 + tid * 8) = va1;
    *(bf16x8*)(Bs + tid * 8)        = vb0;
    *(bf16x8*)(Bs + 2048 + tid * 8) = vb1;
    __syncthreads();

    bf16x8 af[4], bfr[4];
#pragma unroll
    for (int i = 0; i < 4; ++i)
      af[i] = *(const bf16x8*)(As + (wm + i * 16 + l15) * 32 + quad * 8);
#pragma unroll
    for (int j = 0; j < 4; ++j)
      bfr[j] = *(const bf16x8*)(Bs + (wn + j * 16 + l15) * 32 + quad * 8);
#pragma unroll
    for (int i = 0; i < 4; ++i)
#pragma unroll
      for (int j = 0; j < 4; ++j)
        acc[i][j] = MFMA16(af[i], bfr[j], acc[i][j]);
  }

#pragma unroll
  for (int i = 0; i < 4; ++i) {
    const int m = m0 + wm + i * 16 + quad * 4;
#pragma unroll
    for (int j = 0; j < 4; ++j) {
      const int n = n0 + wn + j * 16 + l15;
#pragma unroll
      for (int r = 0; r < 4; ++r)
        C[(size_t)(m + r) * N + n] = acc[i][j][r];
    }
  }
}

// ---------------------------------------------------------------------------
extern "C" void kernel_launch(void* const* d_in, const int* in_sizes, int n_in,
                              void* d_out, int out_size, void* d_ws, size_t ws_size,
                              hipStream_t stream) {
  const float* x  = nullptr;   // 8388608 elems
  const float* wq = nullptr;   // 3145728
  const float* wp = nullptr;   // 1048576
  for (int i = 0; i < n_in; ++i) {
    if      (in_sizes[i] == 8388608) x  = (const float*)d_in[i];
    else if (in_sizes[i] == 3145728) wq = (const float*)d_in[i];
    else if (in_sizes[i] == 1048576) wp = (const float*)d_in[i];
  }
  if (!x || !wq || !wp) {
    x = (const float*)d_in[0]; wq = (const float*)d_in[1]; wp = (const float*)d_in[2];
  }

  float* out = (float*)d_out;            // [4,2048,1024] fp32, written once
  const size_t NE = (size_t)4 * 16 * 2048 * 64;  // 8388608
  bf16* kb = (bf16*)d_ws;                // base 64MB: K, V^T, Q, y
  bf16* vb = kb + NE;                    // V^T: [bh][64][2048]
  bf16* qb = vb + NE;
  bf16* yb = qb + NE;
  // extended region (bf16 copies of inputs)
  bf16* xb  = yb + NE;                   // 8388608 elems
  bf16* wqb = xb + 8388608;              // 3145728
  bf16* wpb = wqb + 3145728;             // 1048576
  const size_t need = (4 * NE + 8388608 + 3145728 + 1048576) * sizeof(bf16);
  const bool ext = ws_size >= need;      // deterministic -> graph-safe

  if (ext) {
    cvt_f32_bf16<<<(8388608 / 8 + 255) / 256, 256, 0, stream>>>(x, xb, 8388608 / 8);
    cvt_f32_bf16<<<(3145728 / 8 + 255) / 256, 256, 0, stream>>>(wq, wqb, 3145728 / 8);
    cvt_f32_bf16<<<(1048576 / 8 + 255) / 256, 256, 0, stream>>>(wp, wpb, 1048576 / 8);
    gemm_qkv_a<<<dim3(24, 64), 256, 0, stream>>>(xb, wqb, qb, kb, vb);
  } else {
    gemm_qkv_f<<<dim3(24, 64), 256, 0, stream>>>(x, wq, qb, kb, vb);
  }

  attn<<<dim3(16, 64), 256, 0, stream>>>(qb, kb, vb, yb);

  if (ext) {
    gemm_proj_a<<<dim3(8, 64), 256, 0, stream>>>(yb, wpb, out);
  } else {
    gemm_proj_f<<<dim3(8, 64), 256, 0, stream>>>(yb, wp, out);
  }
}

// Round 5
// 257.017 us; speedup vs baseline: 1.6565x; 1.0290x over previous
//
#include <hip/hip_runtime.h>
#include <cstdint>
#include <cstddef>

// Pipeline v9. B=4, T=2048, D=1024, H=16, HD=64. Inputs fp32, output fp32.
// attn v7 (unchanged from round-4 kernel): swapped QK^T S^T layout, packed
// cvt_pk P-strip, global_load_lds double-buffered K/V staging, XCD remap.
// NEW: GEMMs get the same 2-phase pipeline attn has (stage(next) async ->
// compute(cur) -> barrier; 1 barrier/K-step instead of 2, latency hidden),
// XCD ownership swizzles (QKV: n-panels per XCD; proj: m-panels per XCD),
// and the 3 cvt launches are fused into one kernel.

typedef __bf16 bf16;
typedef __bf16 bf16x4 __attribute__((ext_vector_type(4)));
typedef __bf16 bf16x8 __attribute__((ext_vector_type(8)));
typedef float  f32x4  __attribute__((ext_vector_type(4)));
typedef float  fvec4  __attribute__((ext_vector_type(4)));
typedef unsigned u32x2 __attribute__((ext_vector_type(2)));

typedef __attribute__((address_space(1))) const void global_cv;
typedef __attribute__((address_space(3))) void lds_v;

#define MFMA16(a, b, c) __builtin_amdgcn_mfma_f32_16x16x32_bf16((a), (b), (c), 0, 0, 0)

// Q scale: 1/sqrt(64) * log2(e)  (softmax done in exp2 domain)
#define QSCALE 0.18033688f

__device__ __forceinline__ void async_ld16(const bf16* g, bf16* l) {
  // gfx950 16B direct global->LDS; dest = wave-uniform base + lane*16.
  __builtin_amdgcn_global_load_lds((global_cv*)g, (lds_v*)l, 16, 0, 0);
}

// XOR chunk swizzle for [rows][64] bf16 LDS tiles (K/V staging + frag reads).
__device__ __forceinline__ int swz_off(int row, int col) {
  int sr = (row & 7) ^ ((row >> 3) & 7);
  return row * 64 + ((((col >> 3) ^ sr) & 7) * 8) + (col & 7);
}

// packed f32x2 -> bf16x2 (no builtin on gfx950; T12 recipe)
__device__ __forceinline__ unsigned cvt_pk(float lo, float hi) {
  unsigned r;
  asm("v_cvt_pk_bf16_f32 %0, %1, %2" : "=v"(r) : "v"(lo), "v"(hi));
  return r;
}

__device__ __forceinline__ bf16x8 cvt8(const float* p) {
  fvec4 u = *(const fvec4*)p;
  fvec4 v = *(const fvec4*)(p + 4);
  bf16x8 r;
  r[0] = (bf16)u[0]; r[1] = (bf16)u[1]; r[2] = (bf16)u[2]; r[3] = (bf16)u[3];
  r[4] = (bf16)v[0]; r[5] = (bf16)v[1]; r[6] = (bf16)v[2]; r[7] = (bf16)v[3];
  return r;
}

// ---------------------------------------------------------------------------
// Fused fp32 -> bf16 bulk convert for x, w_qkv, w_proj (8 elems/thread).
// Ranges (in 8-elem units): x 1048576, wq 393216, wp 131072 -> 1572864 total,
// grid 6144 x 256 exactly.
// ---------------------------------------------------------------------------
__global__ void cvt_all(const float* __restrict__ x, const float* __restrict__ wq,
                        const float* __restrict__ wp, bf16* __restrict__ xb,
                        bf16* __restrict__ wqb, bf16* __restrict__ wpb) {
  int i = blockIdx.x * 256 + threadIdx.x;
  const float* s;
  bf16* d;
  int off;
  if (i < 1048576)      { s = x;  d = xb;  off = i; }
  else if (i < 1441792) { s = wq; d = wqb; off = i - 1048576; }
  else                  { s = wp; d = wpb; off = i - 1441792; }
  *(bf16x8*)(d + (size_t)off * 8) = cvt8(s + (size_t)off * 8);
}

// ---------------------------------------------------------------------------
// Shared epilogue: Q,K as [bh][t][64]; V TRANSPOSED as [bh][d][t].
// ---------------------------------------------------------------------------
__device__ __forceinline__ void qkv_scatter(const f32x4 acc[4][4], int m0, int n0,
                                            int wm, int wn, int quad, int l15,
                                            bf16* Qo, bf16* Ko, bf16* Vo) {
  const int which = n0 >> 10;  // 0=Q 1=K 2=V
  if (which == 2) {
    // V^T: [bh][d][t]; 4 accumulator rows per lane are t-consecutive -> 8B store
#pragma unroll
    for (int i = 0; i < 4; ++i) {
      const int m = m0 + wm + i * 16 + quad * 4;  // multiple of 4, no b-crossing
      const int b = m >> 11;
      const int t = m & 2047;
#pragma unroll
      for (int j = 0; j < 4; ++j) {
        const int n1 = (n0 + wn + j * 16 + l15) & 1023;
        const int h  = n1 >> 6;
        const int d  = n1 & 63;
        bf16x4 v;
#pragma unroll
        for (int r = 0; r < 4; ++r) v[r] = (bf16)acc[i][j][r];
        *(bf16x4*)(Vo + ((size_t)(b * 16 + h) * 64 + d) * 2048 + t) = v;
      }
    }
    return;
  }
  bf16* dst = (which == 0) ? Qo : Ko;
  const float scale = (which == 0) ? QSCALE : 1.0f;
#pragma unroll
  for (int i = 0; i < 4; ++i) {
    const int m = m0 + wm + i * 16 + quad * 4;
#pragma unroll
    for (int j = 0; j < 4; ++j) {
      const int n  = n0 + wn + j * 16 + l15;
      const int n1 = n & 1023;
      const int h  = n1 >> 6;
      const int d  = n1 & 63;
#pragma unroll
      for (int r = 0; r < 4; ++r) {
        const int mm = m + r;
        const int b  = mm >> 11;
        const int t  = mm & 2047;
        dst[(((size_t)(b * 16 + h)) * 2048 + t) * 64 + d] =
            (bf16)(acc[i][j][r] * scale);
      }
    }
  }
}

// ---------------------------------------------------------------------------
// QKV GEMM, bf16, double-buffered async staging. grid (24,64).
// XCD swizzle: XCD c owns n-panels {3c,3c+1,3c+2} (B slice 786KB L2-resident).
// ---------------------------------------------------------------------------
__global__ __launch_bounds__(256, 2)
void gemm_qkv_a(const bf16* __restrict__ A, const bf16* __restrict__ B,
                bf16* __restrict__ Qo, bf16* __restrict__ Ko,
                bf16* __restrict__ Vo) {
  __shared__ __align__(16) bf16 As[2][128 * 32];
  __shared__ __align__(16) bf16 Bs[2][128 * 32];
  const int K = 1024;

  const int tid  = threadIdx.x;
  const int lane = tid & 63;
  const int wave = tid >> 6;
  const int quad = lane >> 4;
  const int l15  = lane & 15;
  const int wm   = (wave >> 1) * 64;
  const int wn   = (wave & 1) * 64;

  const int lin = (int)blockIdx.x + (int)blockIdx.y * 24;
  const int xcd = lin & 7;
  const int sl  = lin >> 3;                 // 0..191
  const int n0  = (xcd * 3 + (sl % 3)) * 128;
  const int m0  = (sl / 3) * 128;

  f32x4 acc[4][4];
#pragma unroll
  for (int i = 0; i < 4; ++i)
#pragma unroll
    for (int j = 0; j < 4; ++j) acc[i][j] = f32x4{0.f, 0.f, 0.f, 0.f};

  const int r0 = tid >> 2;
  const int c0 = (tid & 3) * 8;
  const bf16* ag0 = A + (size_t)(m0 + r0) * K + c0;
  const bf16* ag1 = A + (size_t)(m0 + 64 + r0) * K + c0;
  const bf16* bg0 = B + (size_t)(n0 + r0) * K + c0;
  const bf16* bg1 = B + (size_t)(n0 + 64 + r0) * K + c0;
  const int lo0 = (wave * 64) * 8;        // wave-uniform LDS elem offset
  const int lo1 = (256 + wave * 64) * 8;

  // prologue: stage K-step 0 into buffer 0
  async_ld16(ag0, As[0] + lo0);
  async_ld16(ag1, As[0] + lo1);
  async_ld16(bg0, Bs[0] + lo0);
  async_ld16(bg1, Bs[0] + lo1);
  __syncthreads();

  for (int it = 0; it < 32; ++it) {
    const int cur = it & 1;
    if (it < 31) {  // stage NEXT K-step into the other buffer (async)
      const int kn = (it + 1) * 32;
      async_ld16(ag0 + kn, As[cur ^ 1] + lo0);
      async_ld16(ag1 + kn, As[cur ^ 1] + lo1);
      async_ld16(bg0 + kn, Bs[cur ^ 1] + lo0);
      async_ld16(bg1 + kn, Bs[cur ^ 1] + lo1);
    }

    bf16x8 af[4], bfr[4];
#pragma unroll
    for (int i = 0; i < 4; ++i)
      af[i] = *(const bf16x8*)(As[cur] + (wm + i * 16 + l15) * 32 + quad * 8);
#pragma unroll
    for (int j = 0; j < 4; ++j)
      bfr[j] = *(const bf16x8*)(Bs[cur] + (wn + j * 16 + l15) * 32 + quad * 8);
#pragma unroll
    for (int i = 0; i < 4; ++i)
#pragma unroll
      for (int j = 0; j < 4; ++j)
        acc[i][j] = MFMA16(af[i], bfr[j], acc[i][j]);

    __syncthreads();  // drains staging + protects buffers
  }
  qkv_scatter(acc, m0, n0, wm, wn, quad, l15, Qo, Ko, Vo);
}

// ---------------------------------------------------------------------------
// QKV GEMM, fp32 cvt8 register-staging fallback (plan B). grid (24,64).
// ---------------------------------------------------------------------------
__global__ __launch_bounds__(256, 2)
void gemm_qkv_f(const float* __restrict__ A, const float* __restrict__ B,
                bf16* __restrict__ Qo, bf16* __restrict__ Ko,
                bf16* __restrict__ Vo) {
  __shared__ __align__(16) bf16 As[128 * 32];
  __shared__ __align__(16) bf16 Bs[128 * 32];
  const int K = 1024;

  const int tid  = threadIdx.x;
  const int lane = tid & 63;
  const int wave = tid >> 6;
  const int quad = lane >> 4;
  const int l15  = lane & 15;
  const int wm   = (wave >> 1) * 64;
  const int wn   = (wave & 1) * 64;

  const int lin = (int)blockIdx.x + (int)blockIdx.y * 24;
  const int xcd = lin & 7;
  const int sl  = lin >> 3;
  const int n0  = (xcd * 3 + (sl % 3)) * 128;
  const int m0  = (sl / 3) * 128;

  f32x4 acc[4][4];
#pragma unroll
  for (int i = 0; i < 4; ++i)
#pragma unroll
    for (int j = 0; j < 4; ++j) acc[i][j] = f32x4{0.f, 0.f, 0.f, 0.f};

  const int r0 = tid >> 2;
  const int c0 = (tid & 3) * 8;
  const size_t aoff0 = (size_t)(m0 + r0) * K + c0;
  const size_t aoff1 = (size_t)(m0 + 64 + r0) * K + c0;
  const size_t boff0 = (size_t)(n0 + r0) * K + c0;
  const size_t boff1 = (size_t)(n0 + 64 + r0) * K + c0;

  for (int k0 = 0; k0 < K; k0 += 32) {
    bf16x8 va0 = cvt8(A + aoff0 + k0);
    bf16x8 va1 = cvt8(A + aoff1 + k0);
    bf16x8 vb0 = cvt8(B + boff0 + k0);
    bf16x8 vb1 = cvt8(B + boff1 + k0);
    __syncthreads();
    *(bf16x8*)(As + tid * 8)        = va0;
    *(bf16x8*)(As + 2048 + tid * 8) = va1;
    *(bf16x8*)(Bs + tid * 8)        = vb0;
    *(bf16x8*)(Bs + 2048 + tid * 8) = vb1;
    __syncthreads();

    bf16x8 af[4], bfr[4];
#pragma unroll
    for (int i = 0; i < 4; ++i)
      af[i] = *(const bf16x8*)(As + (wm + i * 16 + l15) * 32 + quad * 8);
#pragma unroll
    for (int j = 0; j < 4; ++j)
      bfr[j] = *(const bf16x8*)(Bs + (wn + j * 16 + l15) * 32 + quad * 8);
#pragma unroll
    for (int i = 0; i < 4; ++i)
#pragma unroll
      for (int j = 0; j < 4; ++j)
        acc[i][j] = MFMA16(af[i], bfr[j], acc[i][j]);
  }
  qkv_scatter(acc, m0, n0, wm, wn, quad, l15, Qo, Ko, Vo);
}

// ---------------------------------------------------------------------------
// Flash attention v7 (unchanged from round-4 kernel). grid (16,64).
// ---------------------------------------------------------------------------
__global__ __launch_bounds__(256, 4)
void attn(const bf16* __restrict__ Q, const bf16* __restrict__ Kk,
          const bf16* __restrict__ Vt, bf16* __restrict__ Y) {
  __shared__ __align__(16) bf16 Ks[2][64 * 64];   // [kv][d] swizzled
  __shared__ __align__(16) bf16 Vs[2][64 * 64];   // [d][kv] swizzled
  __shared__ __align__(16) bf16 Ps[4 * 16 * 64];  // per-wave P strips

  const int tid  = threadIdx.x;
  const int wave = tid >> 6;
  const int lane = tid & 63;
  const int quad = lane >> 4;
  const int l15  = lane & 15;

  // XCD-clustered remap: lin%8 = XCD; each XCD gets heads [8c, 8c+8).
  const int lin  = (int)blockIdx.x + ((int)blockIdx.y << 4);
  const int slot = lin >> 3;                 // 0..127 within XCD
  const int bh   = (lin & 7) * 8 + (slot >> 4);
  const int p    = slot & 15;
  const int b    = bh >> 4;
  const int h    = bh & 15;

  const bf16* Qb = Q  + (size_t)bh * (2048 * 64);
  const bf16* Kb = Kk + (size_t)bh * (2048 * 64);   // [t][64]
  const bf16* Vb = Vt + (size_t)bh * (2048 * 64);   // [64][2048] (transposed)
  char* Pw = (char*)(Ps + wave * (16 * 64));        // 2KB per-wave strip

  // Staging lane constants (pre-swizzled global source, linear LDS dest).
  const int r0s = wave * 8 + (lane >> 3);       // issue-0 row (0..31)
  const int r1s = r0s + 32;                     // issue-1 row (32..63)
  const int qch = lane & 7;
  const int co0 = (((qch ^ ((r0s & 7) ^ ((r0s >> 3) & 7)))) & 7) * 8;
  const int co1 = (((qch ^ ((r1s & 7) ^ ((r1s >> 3) & 7)))) & 7) * 8;
  const bf16* kg0 = Kb + (size_t)r0s * 64 + co0;    // + k0*64 per tile
  const bf16* kg1 = Kb + (size_t)r1s * 64 + co1;
  const bf16* vg0 = Vb + (size_t)r0s * 2048 + co0;  // + k0 per tile
  const bf16* vg1 = Vb + (size_t)r1s * 2048 + co1;
  const int ldsw = wave * 512;                  // wave-uniform elem offset

  // P strip addressing (bytes): row = l15 (128B), 16B chunk C ^= (l15&7).
  const int psx   = l15 & 7;
  const int prowb = l15 * 128;
  const int pr0   = prowb + ((quad ^ psx) << 4);        // PV A-frag k 0..31
  const int pr1   = prowb + (((4 + quad) ^ psx) << 4);  // PV A-frag k 32..63

  const float NEG = -1e30f;

#pragma unroll 1
  for (int pass = 0; pass < 2; ++pass) {
    const int qt = pass ? (31 - p) : p;
    const int q0 = qt * 64;

    const bf16* qp = Qb + (size_t)(q0 + wave * 16 + l15) * 64 + quad * 8;
    bf16x8 qa0 = *(const bf16x8*)qp;
    bf16x8 qa1 = *(const bf16x8*)(qp + 32);

    f32x4 l4 = {0.f, 0.f, 0.f, 0.f};
    f32x4 o[4];
#pragma unroll
    for (int j = 0; j < 4; ++j) o[j] = f32x4{0.f, 0.f, 0.f, 0.f};

    // prologue: stage kv-tile 0 into buffer 0
    async_ld16(kg0, Ks[0] + ldsw);
    async_ld16(kg1, Ks[0] + 2048 + ldsw);
    async_ld16(vg0, Vs[0] + ldsw);
    async_ld16(vg1, Vs[0] + 2048 + ldsw);
    __syncthreads();

#pragma unroll 1
    for (int kt = 0; kt <= qt; ++kt) {
      const int cur = kt & 1;
      const int k0  = kt * 64;

      // stage NEXT tile into the other buffer (async; drains at the barrier)
      if (kt < qt) {
        const int kn = k0 + 64;
        async_ld16(kg0 + (size_t)kn * 64, Ks[cur ^ 1] + ldsw);
        async_ld16(kg1 + (size_t)kn * 64, Ks[cur ^ 1] + 2048 + ldsw);
        async_ld16(vg0 + kn, Vs[cur ^ 1] + ldsw);
        async_ld16(vg1 + kn, Vs[cur ^ 1] + 2048 + ldsw);
      }

      // S^T = K Q^T (log2 domain via QSCALE): lane -> q-row = l15,
      // k = k0 + 16j + 4*quad + r.
      f32x4 s[4];
      __builtin_amdgcn_s_setprio(1);
#pragma unroll
      for (int j = 0; j < 4; ++j) {
        const int kvr = j * 16 + l15;
        bf16x8 k0f = *(const bf16x8*)(Ks[cur] + swz_off(kvr, quad * 8));
        bf16x8 k1f = *(const bf16x8*)(Ks[cur] + swz_off(kvr, 32 + quad * 8));
        f32x4 z = {0.f, 0.f, 0.f, 0.f};
        z = MFMA16(k0f, qa0, z);   // swapped: A=K, B=Q -> C = S^T
        z = MFMA16(k1f, qa1, z);
        s[j] = z;
      }
      __builtin_amdgcn_s_setprio(0);

      if (kt == qt) {  // diagonal: causal mask (k_local > q_local)
        const int qloc = wave * 16 + l15;
#pragma unroll
        for (int j = 0; j < 4; ++j) {
#pragma unroll
          for (int r = 0; r < 4; ++r) {
            if (16 * j + 4 * quad + r > qloc) s[j][r] = NEG;
          }
        }
      }

      // p = exp2(s); vector-accumulate l partials (all same q-row = l15)
#pragma unroll
      for (int j = 0; j < 4; ++j) {
#pragma unroll
        for (int r = 0; r < 4; ++r) s[j][r] = exp2f(s[j][r]);
        l4 += s[j];
      }

      // P strip: 4 packed 8B writes (k = 16j+4*quad .. +3), chunk-swizzled.
#pragma unroll
      for (int j = 0; j < 4; ++j) {
        u32x2 pk;
        pk[0] = cvt_pk(s[j][0], s[j][1]);
        pk[1] = cvt_pk(s[j][2], s[j][3]);
        const int C = 2 * j + (quad >> 1);
        *(u32x2*)(Pw + prowb + (((C ^ psx) << 4) | ((quad & 1) << 3))) = pk;
      }

      bf16x8 pf0 = *(const bf16x8*)(Pw + pr0);
      bf16x8 pf1 = *(const bf16x8*)(Pw + pr1);

      // PV from V^T tile
      __builtin_amdgcn_s_setprio(1);
#pragma unroll
      for (int j = 0; j < 4; ++j) {
        const int d = j * 16 + l15;
        bf16x8 vf0 = *(const bf16x8*)(Vs[cur] + swz_off(d, quad * 8));
        bf16x8 vf1 = *(const bf16x8*)(Vs[cur] + swz_off(d, 32 + quad * 8));
        o[j] = MFMA16(pf0, vf0, o[j]);
        o[j] = MFMA16(pf1, vf1, o[j]);
      }
      __builtin_amdgcn_s_setprio(0);

      __syncthreads();  // drains staging (vmcnt) + protects both buffers
    }

    // l: fold 4 components (same q-row), reduce across quads, redistribute.
    float lf = (l4[0] + l4[1]) + (l4[2] + l4[3]);
    lf += __shfl_xor(lf, 16);
    lf += __shfl_xor(lf, 32);
    float inv[4];
#pragma unroll
    for (int r = 0; r < 4; ++r) inv[r] = 1.0f / __shfl(lf, quad * 4 + r);

#pragma unroll
    for (int j = 0; j < 4; ++j) {
      const int dcol = h * 64 + j * 16 + l15;
#pragma unroll
      for (int r = 0; r < 4; ++r) {
        const int trow = q0 + wave * 16 + quad * 4 + r;
        Y[((size_t)b * 2048 + trow) * 1024 + dcol] = (bf16)(o[j][r] * inv[r]);
      }
    }
  }
}

// ---------------------------------------------------------------------------
// Projection GEMM, bf16, double-buffered async staging: out fp32 = y*wpb^T.
// grid (8,64). XCD swizzle: XCD c owns m-panels 8c..8c+7 (B 2MB L2-resident).
// ---------------------------------------------------------------------------
__global__ __launch_bounds__(256, 2)
void gemm_proj_a(const bf16* __restrict__ A, const bf16* __restrict__ B,
                 float* __restrict__ C) {
  __shared__ __align__(16) bf16 As[2][128 * 32];
  __shared__ __align__(16) bf16 Bs[2][128 * 32];
  const int K = 1024, N = 1024;

  const int tid  = threadIdx.x;
  const int lane = tid & 63;
  const int wave = tid >> 6;
  const int quad = lane >> 4;
  const int l15  = lane & 15;
  const int wm   = (wave >> 1) * 64;
  const int wn   = (wave & 1) * 64;

  const int lin = (int)blockIdx.x + (int)blockIdx.y * 8;
  const int xcd = lin & 7;
  const int sl  = lin >> 3;                 // 0..63
  const int m0  = (xcd * 8 + (sl & 7)) * 128;
  const int n0  = (sl >> 3) * 128;

  f32x4 acc[4][4];
#pragma unroll
  for (int i = 0; i < 4; ++i)
#pragma unroll
    for (int j = 0; j < 4; ++j) acc[i][j] = f32x4{0.f, 0.f, 0.f, 0.f};

  const int r0 = tid >> 2;
  const int c0 = (tid & 3) * 8;
  const bf16* ag0 = A + (size_t)(m0 + r0) * K + c0;
  const bf16* ag1 = A + (size_t)(m0 + 64 + r0) * K + c0;
  const bf16* bg0 = B + (size_t)(n0 + r0) * K + c0;
  const bf16* bg1 = B + (size_t)(n0 + 64 + r0) * K + c0;
  const int lo0 = (wave * 64) * 8;
  const int lo1 = (256 + wave * 64) * 8;

  // prologue: stage K-step 0 into buffer 0
  async_ld16(ag0, As[0] + lo0);
  async_ld16(ag1, As[0] + lo1);
  async_ld16(bg0, Bs[0] + lo0);
  async_ld16(bg1, Bs[0] + lo1);
  __syncthreads();

  for (int it = 0; it < 32; ++it) {
    const int cur = it & 1;
    if (it < 31) {
      const int kn = (it + 1) * 32;
      async_ld16(ag0 + kn, As[cur ^ 1] + lo0);
      async_ld16(ag1 + kn, As[cur ^ 1] + lo1);
      async_ld16(bg0 + kn, Bs[cur ^ 1] + lo0);
      async_ld16(bg1 + kn, Bs[cur ^ 1] + lo1);
    }

    bf16x8 af[4], bfr[4];
#pragma unroll
    for (int i = 0; i < 4; ++i)
      af[i] = *(const bf16x8*)(As[cur] + (wm + i * 16 + l15) * 32 + quad * 8);
#pragma unroll
    for (int j = 0; j < 4; ++j)
      bfr[j] = *(const bf16x8*)(Bs[cur] + (wn + j * 16 + l15) * 32 + quad * 8);
#pragma unroll
    for (int i = 0; i < 4; ++i)
#pragma unroll
      for (int j = 0; j < 4; ++j)
        acc[i][j] = MFMA16(af[i], bfr[j], acc[i][j]);

    __syncthreads();
  }

#pragma unroll
  for (int i = 0; i < 4; ++i) {
    const int m = m0 + wm + i * 16 + quad * 4;
#pragma unroll
    for (int j = 0; j < 4; ++j) {
      const int n = n0 + wn + j * 16 + l15;
#pragma unroll
      for (int r = 0; r < 4; ++r)
        C[(size_t)(m + r) * N + n] = acc[i][j][r];
    }
  }
}

// ---------------------------------------------------------------------------
// Projection GEMM, fp32-B fallback (plan B). grid (8,64).
// ---------------------------------------------------------------------------
__global__ __launch_bounds__(256, 2)
void gemm_proj_f(const bf16* __restrict__ A, const float* __restrict__ B,
                 float* __restrict__ C) {
  __shared__ __align__(16) bf16 As[128 * 32];
  __shared__ __align__(16) bf16 Bs[128 * 32];
  const int K = 1024, N = 1024;

  const int tid  = threadIdx.x;
  const int lane = tid & 63;
  const int wave = tid >> 6;
  const int quad = lane >> 4;
  const int l15  = lane & 15;
  const int wm   = (wave >> 1) * 64;
  const int wn   = (wave & 1) * 64;

  const int lin = (int)blockIdx.x + (int)blockIdx.y * 8;
  const int xcd = lin & 7;
  const int sl  = lin >> 3;
  const int m0  = (xcd * 8 + (sl & 7)) * 128;
  const int n0  = (sl >> 3) * 128;

  f32x4 acc[4][4];
#pragma unroll
  for (int i = 0; i < 4; ++i)
#pragma unroll
    for (int j = 0; j < 4; ++j) acc[i][j] = f32x4{0.f, 0.f, 0.f, 0.f};

  const int r0 = tid >> 2;
  const int c0 = (tid & 3) * 8;
  const size_t aoff0 = (size_t)(m0 + r0) * K + c0;
  const size_t aoff1 = (size_t)(m0 + 64 + r0) * K + c0;
  const size_t boff0 = (size_t)(n0 + r0) * K + c0;
  const size_t boff1 = (size_t)(n0 + 64 + r0) * K + c0;

  for (int k0 = 0; k0 < K; k0 += 32) {
    bf16x8 va0 = *(const bf16x8*)(A + aoff0 + k0);
    bf16x8 va1 = *(const bf16x8*)(A + aoff1 + k0);
    bf16x8 vb0 = cvt8(B + boff0 + k0);
    bf16x8 vb1 = cvt8(B + boff1 + k0);
    __syncthreads();
    *(bf16x8*)(As + tid * 8)        = va0;
    *(bf16x8*)(As + 2048 + tid * 8) = va1;
    *(bf16x8*)(Bs + tid * 8)        = vb0;
    *(bf16x8*)(Bs + 2048 + tid * 8) = vb1;
    __syncthreads();

    bf16x8 af[4], bfr[4];
#pragma unroll
    for (int i = 0; i < 4; ++i)
      af[i] = *(const bf16x8*)(As + (wm + i * 16 + l15) * 32 + quad * 8);
#pragma unroll
    for (int j = 0; j < 4; ++j)
      bfr[j] = *(const bf16x8*)(Bs + (wn + j * 16 + l15) * 32 + quad * 8);
#pragma unroll
    for (int i = 0; i < 4; ++i)
#pragma unroll
      for (int j = 0; j < 4; ++j)
        acc[i][j] = MFMA16(af[i], bfr[j], acc[i][j]);
  }

#pragma unroll
  for (int i = 0; i < 4; ++i) {
    const int m = m0 + wm + i * 16 + quad * 4;
#pragma unroll
    for (int j = 0; j < 4; ++j) {
      const int n = n0 + wn + j * 16 + l15;
#pragma unroll
      for (int r = 0; r < 4; ++r)
        C[(size_t)(m + r) * N + n] = acc[i][j][r];
    }
  }
}

// ---------------------------------------------------------------------------
extern "C" void kernel_launch(void* const* d_in, const int* in_sizes, int n_in,
                              void* d_out, int out_size, void* d_ws, size_t ws_size,
                              hipStream_t stream) {
  const float* x  = nullptr;   // 8388608 elems
  const float* wq = nullptr;   // 3145728
  const float* wp = nullptr;   // 1048576
  for (int i = 0; i < n_in; ++i) {
    if      (in_sizes[i] == 8388608) x  = (const float*)d_in[i];
    else if (in_sizes[i] == 3145728) wq = (const float*)d_in[i];
    else if (in_sizes[i] == 1048576) wp = (const float*)d_in[i];
  }
  if (!x || !wq || !wp) {
    x = (const float*)d_in[0]; wq = (const float*)d_in[1]; wp = (const float*)d_in[2];
  }

  float* out = (float*)d_out;            // [4,2048,1024] fp32, written once
  const size_t NE = (size_t)4 * 16 * 2048 * 64;  // 8388608
  bf16* kb = (bf16*)d_ws;                // base 64MB: K, V^T, Q, y
  bf16* vb = kb + NE;                    // V^T: [bh][64][2048]
  bf16* qb = vb + NE;
  bf16* yb = qb + NE;
  // extended region (bf16 copies of inputs)
  bf16* xb  = yb + NE;                   // 8388608 elems
  bf16* wqb = xb + 8388608;              // 3145728
  bf16* wpb = wqb + 3145728;             // 1048576
  const size_t need = (4 * NE + 8388608 + 3145728 + 1048576) * sizeof(bf16);
  const bool ext = ws_size >= need;      // deterministic -> graph-safe

  if (ext) {
    cvt_all<<<6144, 256, 0, stream>>>(x, wq, wp, xb, wqb, wpb);
    gemm_qkv_a<<<dim3(24, 64), 256, 0, stream>>>(xb, wqb, qb, kb, vb);
  } else {
    gemm_qkv_f<<<dim3(24, 64), 256, 0, stream>>>(x, wq, qb, kb, vb);
  }

  attn<<<dim3(16, 64), 256, 0, stream>>>(qb, kb, vb, yb);

  if (ext) {
    gemm_proj_a<<<dim3(8, 64), 256, 0, stream>>>(yb, wpb, out);
  } else {
    gemm_proj_f<<<dim3(8, 64), 256, 0, stream>>>(yb, wp, out);
  }
}

// Round 7
// 241.618 us; speedup vs baseline: 1.7620x; 1.0637x over previous
//
#include <hip/hip_runtime.h>
#include <cstdint>
#include <cstddef>

// Pipeline v12 (bisect round). B=4, T=2048, D=1024, H=16, HD=64.
// attn: EXACT revert to the round-4/5 passing version (84us) with a single
// delta: exp2f -> inline-asm v_exp_f32 (exact same 2^x semantics).
// GEMMs: keep v11 rewrite (flat dbuf LDS, hoisted frag offsets + i*1024
// immediates, pointer-incremented staging, launch_bounds(256,3)).
// If this round fails -> GEMM rewrite guilty; if passes -> v11 attn was.

typedef __bf16 bf16;
typedef __bf16 bf16x4 __attribute__((ext_vector_type(4)));
typedef __bf16 bf16x8 __attribute__((ext_vector_type(8)));
typedef float  f32x4  __attribute__((ext_vector_type(4)));
typedef float  fvec4  __attribute__((ext_vector_type(4)));
typedef unsigned u32x2 __attribute__((ext_vector_type(2)));

typedef __attribute__((address_space(1))) const void global_cv;
typedef __attribute__((address_space(3))) void lds_v;

#define MFMA16(a, b, c) __builtin_amdgcn_mfma_f32_16x16x32_bf16((a), (b), (c), 0, 0, 0)

// Q scale: 1/sqrt(64) * log2(e)  (softmax done in exp2 domain)
#define QSCALE 0.18033688f

__device__ __forceinline__ void async_ld16(const bf16* g, bf16* l) {
  __builtin_amdgcn_global_load_lds((global_cv*)g, (lds_v*)l, 16, 0, 0);
}

// XOR chunk swizzle for [rows][64] bf16 LDS tiles (attn staging + frag reads).
__device__ __forceinline__ int swz_off(int row, int col) {
  int sr = (row & 7) ^ ((row >> 3) & 7);
  return row * 64 + ((((col >> 3) ^ sr) & 7) * 8) + (col & 7);
}

// packed f32x2 -> bf16x2
__device__ __forceinline__ unsigned cvt_pk(float lo, float hi) {
  unsigned r;
  asm("v_cvt_pk_bf16_f32 %0, %1, %2" : "=v"(r) : "v"(lo), "v"(hi));
  return r;
}

// exact v_exp_f32 (2^x), no libm fixup path
__device__ __forceinline__ float exp2_fast(float x) {
  float r;
  asm("v_exp_f32 %0, %1" : "=v"(r) : "v"(x));
  return r;
}

__device__ __forceinline__ bf16x8 cvt8(const float* p) {
  fvec4 u = *(const fvec4*)p;
  fvec4 v = *(const fvec4*)(p + 4);
  bf16x8 r;
  r[0] = (bf16)u[0]; r[1] = (bf16)u[1]; r[2] = (bf16)u[2]; r[3] = (bf16)u[3];
  r[4] = (bf16)v[0]; r[5] = (bf16)v[1]; r[6] = (bf16)v[2]; r[7] = (bf16)v[3];
  return r;
}

// ---------------------------------------------------------------------------
// Fused fp32 -> bf16 bulk convert (8 elems/thread). grid 6144 x 256 exact.
// ---------------------------------------------------------------------------
__global__ void cvt_all(const float* __restrict__ x, const float* __restrict__ wq,
                        const float* __restrict__ wp, bf16* __restrict__ xb,
                        bf16* __restrict__ wqb, bf16* __restrict__ wpb) {
  int i = blockIdx.x * 256 + threadIdx.x;
  const float* s;
  bf16* d;
  int off;
  if (i < 1048576)      { s = x;  d = xb;  off = i; }
  else if (i < 1441792) { s = wq; d = wqb; off = i - 1048576; }
  else                  { s = wp; d = wpb; off = i - 1441792; }
  *(bf16x8*)(d + (size_t)off * 8) = cvt8(s + (size_t)off * 8);
}

// ---------------------------------------------------------------------------
// Shared epilogue: Q,K as [bh][t][64]; V TRANSPOSED as [bh][d][t].
// ---------------------------------------------------------------------------
__device__ __forceinline__ void qkv_scatter(const f32x4 acc[4][4], int m0, int n0,
                                            int wm, int wn, int quad, int l15,
                                            bf16* Qo, bf16* Ko, bf16* Vo) {
  const int which = n0 >> 10;  // 0=Q 1=K 2=V
  if (which == 2) {
#pragma unroll
    for (int i = 0; i < 4; ++i) {
      const int m = m0 + wm + i * 16 + quad * 4;
      const int b = m >> 11;
      const int t = m & 2047;
#pragma unroll
      for (int j = 0; j < 4; ++j) {
        const int n1 = (n0 + wn + j * 16 + l15) & 1023;
        const int h  = n1 >> 6;
        const int d  = n1 & 63;
        bf16x4 v;
#pragma unroll
        for (int r = 0; r < 4; ++r) v[r] = (bf16)acc[i][j][r];
        *(bf16x4*)(Vo + ((size_t)(b * 16 + h) * 64 + d) * 2048 + t) = v;
      }
    }
    return;
  }
  bf16* dst = (which == 0) ? Qo : Ko;
  const float scale = (which == 0) ? QSCALE : 1.0f;
#pragma unroll
  for (int i = 0; i < 4; ++i) {
    const int m = m0 + wm + i * 16 + quad * 4;
#pragma unroll
    for (int j = 0; j < 4; ++j) {
      const int n  = n0 + wn + j * 16 + l15;
      const int n1 = n & 1023;
      const int h  = n1 >> 6;
      const int d  = n1 & 63;
#pragma unroll
      for (int r = 0; r < 4; ++r) {
        const int mm = m + r;
        const int b  = mm >> 11;
        const int t  = mm & 2047;
        dst[(((size_t)(b * 16 + h)) * 2048 + t) * 64 + d] =
            (bf16)(acc[i][j][r] * scale);
      }
    }
  }
}

// ---------------------------------------------------------------------------
// QKV GEMM, bf16, double-buffered async staging (v11 form). grid (24,64).
// ---------------------------------------------------------------------------
__global__ __launch_bounds__(256, 3)
void gemm_qkv_a(const bf16* __restrict__ A, const bf16* __restrict__ B,
                bf16* __restrict__ Qo, bf16* __restrict__ Ko,
                bf16* __restrict__ Vo) {
  __shared__ __align__(16) bf16 As[2 * 128 * 32];
  __shared__ __align__(16) bf16 Bs[2 * 128 * 32];
  const int K = 1024;

  const int tid  = threadIdx.x;
  const int lane = tid & 63;
  const int wave = tid >> 6;
  const int quad = lane >> 4;
  const int l15  = lane & 15;
  const int wm   = (wave >> 1) * 64;
  const int wn   = (wave & 1) * 64;

  const int lin = (int)blockIdx.x + (int)blockIdx.y * 24;
  const int xcd = lin & 7;
  const int sl  = lin >> 3;
  const int n0  = (xcd * 3 + (sl % 3)) * 128;
  const int m0  = (sl / 3) * 128;

  f32x4 acc[4][4];
#pragma unroll
  for (int i = 0; i < 4; ++i)
#pragma unroll
    for (int j = 0; j < 4; ++j) acc[i][j] = f32x4{0.f, 0.f, 0.f, 0.f};

  const int r0 = tid >> 2;
  const int c0 = (tid & 3) * 8;
  const bf16* ag0 = A + (size_t)(m0 + r0) * K + c0;
  const bf16* ag1 = A + (size_t)(m0 + 64 + r0) * K + c0;
  const bf16* bg0 = B + (size_t)(n0 + r0) * K + c0;
  const bf16* bg1 = B + (size_t)(n0 + 64 + r0) * K + c0;
  const int lo0 = (wave * 64) * 8;
  const int lo1 = (256 + wave * 64) * 8;

  const int afb = (wm + l15) * 64 + quad * 16;
  const int bfb = (wn + l15) * 64 + quad * 16;

  async_ld16(ag0, As + lo0);
  async_ld16(ag1, As + lo1);
  async_ld16(bg0, Bs + lo0);
  async_ld16(bg1, Bs + lo1);
  ag0 += 32; ag1 += 32; bg0 += 32; bg1 += 32;
  __syncthreads();

  for (int it = 0; it < 32; ++it) {
    const int cur = it & 1;
    if (it < 31) {
      const int nb = (cur ^ 1) << 12;
      async_ld16(ag0, As + nb + lo0);
      async_ld16(ag1, As + nb + lo1);
      async_ld16(bg0, Bs + nb + lo0);
      async_ld16(bg1, Bs + nb + lo1);
      ag0 += 32; ag1 += 32; bg0 += 32; bg1 += 32;
    }

    const char* pA = (const char*)As + (cur << 13) + afb;
    const char* pB = (const char*)Bs + (cur << 13) + bfb;
    bf16x8 af[4], bfr[4];
#pragma unroll
    for (int i = 0; i < 4; ++i) af[i] = *(const bf16x8*)(pA + i * 1024);
#pragma unroll
    for (int j = 0; j < 4; ++j) bfr[j] = *(const bf16x8*)(pB + j * 1024);
#pragma unroll
    for (int i = 0; i < 4; ++i)
#pragma unroll
      for (int j = 0; j < 4; ++j)
        acc[i][j] = MFMA16(af[i], bfr[j], acc[i][j]);

    __syncthreads();
  }
  qkv_scatter(acc, m0, n0, wm, wn, quad, l15, Qo, Ko, Vo);
}

// ---------------------------------------------------------------------------
// QKV GEMM, fp32 cvt8 register-staging fallback. grid (24,64).
// ---------------------------------------------------------------------------
__global__ __launch_bounds__(256, 2)
void gemm_qkv_f(const float* __restrict__ A, const float* __restrict__ B,
                bf16* __restrict__ Qo, bf16* __restrict__ Ko,
                bf16* __restrict__ Vo) {
  __shared__ __align__(16) bf16 As[128 * 32];
  __shared__ __align__(16) bf16 Bs[128 * 32];
  const int K = 1024;

  const int tid  = threadIdx.x;
  const int lane = tid & 63;
  const int wave = tid >> 6;
  const int quad = lane >> 4;
  const int l15  = lane & 15;
  const int wm   = (wave >> 1) * 64;
  const int wn   = (wave & 1) * 64;

  const int lin = (int)blockIdx.x + (int)blockIdx.y * 24;
  const int xcd = lin & 7;
  const int sl  = lin >> 3;
  const int n0  = (xcd * 3 + (sl % 3)) * 128;
  const int m0  = (sl / 3) * 128;

  f32x4 acc[4][4];
#pragma unroll
  for (int i = 0; i < 4; ++i)
#pragma unroll
    for (int j = 0; j < 4; ++j) acc[i][j] = f32x4{0.f, 0.f, 0.f, 0.f};

  const int r0 = tid >> 2;
  const int c0 = (tid & 3) * 8;
  const size_t aoff0 = (size_t)(m0 + r0) * K + c0;
  const size_t aoff1 = (size_t)(m0 + 64 + r0) * K + c0;
  const size_t boff0 = (size_t)(n0 + r0) * K + c0;
  const size_t boff1 = (size_t)(n0 + 64 + r0) * K + c0;

  for (int k0 = 0; k0 < K; k0 += 32) {
    bf16x8 va0 = cvt8(A + aoff0 + k0);
    bf16x8 va1 = cvt8(A + aoff1 + k0);
    bf16x8 vb0 = cvt8(B + boff0 + k0);
    bf16x8 vb1 = cvt8(B + boff1 + k0);
    __syncthreads();
    *(bf16x8*)(As + tid * 8)        = va0;
    *(bf16x8*)(As + 2048 + tid * 8) = va1;
    *(bf16x8*)(Bs + tid * 8)        = vb0;
    *(bf16x8*)(Bs + 2048 + tid * 8) = vb1;
    __syncthreads();

    bf16x8 af[4], bfr[4];
#pragma unroll
    for (int i = 0; i < 4; ++i)
      af[i] = *(const bf16x8*)(As + (wm + i * 16 + l15) * 32 + quad * 8);
#pragma unroll
    for (int j = 0; j < 4; ++j)
      bfr[j] = *(const bf16x8*)(Bs + (wn + j * 16 + l15) * 32 + quad * 8);
#pragma unroll
    for (int i = 0; i < 4; ++i)
#pragma unroll
      for (int j = 0; j < 4; ++j)
        acc[i][j] = MFMA16(af[i], bfr[j], acc[i][j]);
  }
  qkv_scatter(acc, m0, n0, wm, wn, quad, l15, Qo, Ko, Vo);
}

// ---------------------------------------------------------------------------
// Flash attention — EXACT round-4/5 passing version; single delta: exp2_fast.
// grid (16,64), XCD-clustered remap; q-tiles {p, 31-p}.
// ---------------------------------------------------------------------------
__global__ __launch_bounds__(256, 4)
void attn(const bf16* __restrict__ Q, const bf16* __restrict__ Kk,
          const bf16* __restrict__ Vt, bf16* __restrict__ Y) {
  __shared__ __align__(16) bf16 Ks[2][64 * 64];   // [kv][d] swizzled
  __shared__ __align__(16) bf16 Vs[2][64 * 64];   // [d][kv] swizzled
  __shared__ __align__(16) bf16 Ps[4 * 16 * 64];  // per-wave P strips

  const int tid  = threadIdx.x;
  const int wave = tid >> 6;
  const int lane = tid & 63;
  const int quad = lane >> 4;
  const int l15  = lane & 15;

  const int lin  = (int)blockIdx.x + ((int)blockIdx.y << 4);
  const int slot = lin >> 3;
  const int bh   = (lin & 7) * 8 + (slot >> 4);
  const int p    = slot & 15;
  const int b    = bh >> 4;
  const int h    = bh & 15;

  const bf16* Qb = Q  + (size_t)bh * (2048 * 64);
  const bf16* Kb = Kk + (size_t)bh * (2048 * 64);   // [t][64]
  const bf16* Vb = Vt + (size_t)bh * (2048 * 64);   // [64][2048] (transposed)
  char* Pw = (char*)(Ps + wave * (16 * 64));        // 2KB per-wave strip

  const int r0s = wave * 8 + (lane >> 3);       // issue-0 row (0..31)
  const int r1s = r0s + 32;                     // issue-1 row (32..63)
  const int qch = lane & 7;
  const int co0 = (((qch ^ ((r0s & 7) ^ ((r0s >> 3) & 7)))) & 7) * 8;
  const int co1 = (((qch ^ ((r1s & 7) ^ ((r1s >> 3) & 7)))) & 7) * 8;
  const bf16* kg0 = Kb + (size_t)r0s * 64 + co0;    // + k0*64 per tile
  const bf16* kg1 = Kb + (size_t)r1s * 64 + co1;
  const bf16* vg0 = Vb + (size_t)r0s * 2048 + co0;  // + k0 per tile
  const bf16* vg1 = Vb + (size_t)r1s * 2048 + co1;
  const int ldsw = wave * 512;                  // wave-uniform elem offset

  // P strip addressing (bytes): row = l15 (128B), 16B chunk C ^= (l15&7).
  const int psx   = l15 & 7;
  const int prowb = l15 * 128;
  const int pr0   = prowb + ((quad ^ psx) << 4);        // PV A-frag k 0..31
  const int pr1   = prowb + (((4 + quad) ^ psx) << 4);  // PV A-frag k 32..63

  const float NEG = -1e30f;

#pragma unroll 1
  for (int pass = 0; pass < 2; ++pass) {
    const int qt = pass ? (31 - p) : p;
    const int q0 = qt * 64;

    const bf16* qp = Qb + (size_t)(q0 + wave * 16 + l15) * 64 + quad * 8;
    bf16x8 qa0 = *(const bf16x8*)qp;
    bf16x8 qa1 = *(const bf16x8*)(qp + 32);

    f32x4 l4 = {0.f, 0.f, 0.f, 0.f};
    f32x4 o[4];
#pragma unroll
    for (int j = 0; j < 4; ++j) o[j] = f32x4{0.f, 0.f, 0.f, 0.f};

    // prologue: stage kv-tile 0 into buffer 0
    async_ld16(kg0, Ks[0] + ldsw);
    async_ld16(kg1, Ks[0] + 2048 + ldsw);
    async_ld16(vg0, Vs[0] + ldsw);
    async_ld16(vg1, Vs[0] + 2048 + ldsw);
    __syncthreads();

#pragma unroll 1
    for (int kt = 0; kt <= qt; ++kt) {
      const int cur = kt & 1;
      const int k0  = kt * 64;

      if (kt < qt) {
        const int kn = k0 + 64;
        async_ld16(kg0 + (size_t)kn * 64, Ks[cur ^ 1] + ldsw);
        async_ld16(kg1 + (size_t)kn * 64, Ks[cur ^ 1] + 2048 + ldsw);
        async_ld16(vg0 + kn, Vs[cur ^ 1] + ldsw);
        async_ld16(vg1 + kn, Vs[cur ^ 1] + 2048 + ldsw);
      }

      // S^T = K Q^T (log2 domain via QSCALE): lane -> q = l15,
      // k = k0 + 16j + 4*quad + r.
      f32x4 s[4];
      __builtin_amdgcn_s_setprio(1);
#pragma unroll
      for (int j = 0; j < 4; ++j) {
        const int kvr = j * 16 + l15;
        bf16x8 k0f = *(const bf16x8*)(Ks[cur] + swz_off(kvr, quad * 8));
        bf16x8 k1f = *(const bf16x8*)(Ks[cur] + swz_off(kvr, 32 + quad * 8));
        f32x4 z = {0.f, 0.f, 0.f, 0.f};
        z = MFMA16(k0f, qa0, z);
        z = MFMA16(k1f, qa1, z);
        s[j] = z;
      }
      __builtin_amdgcn_s_setprio(0);

      if (kt == qt) {  // diagonal: causal mask (k_local > q_local)
        const int qloc = wave * 16 + l15;
#pragma unroll
        for (int j = 0; j < 4; ++j) {
#pragma unroll
          for (int r = 0; r < 4; ++r) {
            if (16 * j + 4 * quad + r > qloc) s[j][r] = NEG;
          }
        }
      }

      // p = exp2(s) via v_exp_f32; accumulate l partials
#pragma unroll
      for (int j = 0; j < 4; ++j) {
#pragma unroll
        for (int r = 0; r < 4; ++r) s[j][r] = exp2_fast(s[j][r]);
        l4 += s[j];
      }

      // P strip: 4 packed 8B writes (k = 16j+4*quad .. +3), chunk-swizzled.
#pragma unroll
      for (int j = 0; j < 4; ++j) {
        u32x2 pk;
        pk[0] = cvt_pk(s[j][0], s[j][1]);
        pk[1] = cvt_pk(s[j][2], s[j][3]);
        const int C = 2 * j + (quad >> 1);
        *(u32x2*)(Pw + prowb + (((C ^ psx) << 4) | ((quad & 1) << 3))) = pk;
      }

      bf16x8 pf0 = *(const bf16x8*)(Pw + pr0);
      bf16x8 pf1 = *(const bf16x8*)(Pw + pr1);

      // PV from V^T tile
      __builtin_amdgcn_s_setprio(1);
#pragma unroll
      for (int j = 0; j < 4; ++j) {
        const int d = j * 16 + l15;
        bf16x8 vf0 = *(const bf16x8*)(Vs[cur] + swz_off(d, quad * 8));
        bf16x8 vf1 = *(const bf16x8*)(Vs[cur] + swz_off(d, 32 + quad * 8));
        o[j] = MFMA16(pf0, vf0, o[j]);
        o[j] = MFMA16(pf1, vf1, o[j]);
      }
      __builtin_amdgcn_s_setprio(0);

      __syncthreads();  // drains staging (vmcnt) + protects both buffers
    }

    // l: fold 4 components, reduce across quads, redistribute.
    float lf = (l4[0] + l4[1]) + (l4[2] + l4[3]);
    lf += __shfl_xor(lf, 16);
    lf += __shfl_xor(lf, 32);
    float inv[4];
#pragma unroll
    for (int r = 0; r < 4; ++r) inv[r] = 1.0f / __shfl(lf, quad * 4 + r);

#pragma unroll
    for (int j = 0; j < 4; ++j) {
      const int dcol = h * 64 + j * 16 + l15;
#pragma unroll
      for (int r = 0; r < 4; ++r) {
        const int trow = q0 + wave * 16 + quad * 4 + r;
        Y[((size_t)b * 2048 + trow) * 1024 + dcol] = (bf16)(o[j][r] * inv[r]);
      }
    }
  }
}

// ---------------------------------------------------------------------------
// Projection GEMM, bf16, double-buffered async staging (v11 form). grid (8,64).
// ---------------------------------------------------------------------------
__global__ __launch_bounds__(256, 3)
void gemm_proj_a(const bf16* __restrict__ A, const bf16* __restrict__ B,
                 float* __restrict__ C) {
  __shared__ __align__(16) bf16 As[2 * 128 * 32];
  __shared__ __align__(16) bf16 Bs[2 * 128 * 32];
  const int K = 1024, N = 1024;

  const int tid  = threadIdx.x;
  const int lane = tid & 63;
  const int wave = tid >> 6;
  const int quad = lane >> 4;
  const int l15  = lane & 15;
  const int wm   = (wave >> 1) * 64;
  const int wn   = (wave & 1) * 64;

  const int lin = (int)blockIdx.x + (int)blockIdx.y * 8;
  const int xcd = lin & 7;
  const int sl  = lin >> 3;
  const int m0  = (xcd * 8 + (sl & 7)) * 128;
  const int n0  = (sl >> 3) * 128;

  f32x4 acc[4][4];
#pragma unroll
  for (int i = 0; i < 4; ++i)
#pragma unroll
    for (int j = 0; j < 4; ++j) acc[i][j] = f32x4{0.f, 0.f, 0.f, 0.f};

  const int r0 = tid >> 2;
  const int c0 = (tid & 3) * 8;
  const bf16* ag0 = A + (size_t)(m0 + r0) * K + c0;
  const bf16* ag1 = A + (size_t)(m0 + 64 + r0) * K + c0;
  const bf16* bg0 = B + (size_t)(n0 + r0) * K + c0;
  const bf16* bg1 = B + (size_t)(n0 + 64 + r0) * K + c0;
  const int lo0 = (wave * 64) * 8;
  const int lo1 = (256 + wave * 64) * 8;

  const int afb = (wm + l15) * 64 + quad * 16;
  const int bfb = (wn + l15) * 64 + quad * 16;

  async_ld16(ag0, As + lo0);
  async_ld16(ag1, As + lo1);
  async_ld16(bg0, Bs + lo0);
  async_ld16(bg1, Bs + lo1);
  ag0 += 32; ag1 += 32; bg0 += 32; bg1 += 32;
  __syncthreads();

  for (int it = 0; it < 32; ++it) {
    const int cur = it & 1;
    if (it < 31) {
      const int nb = (cur ^ 1) << 12;
      async_ld16(ag0, As + nb + lo0);
      async_ld16(ag1, As + nb + lo1);
      async_ld16(bg0, Bs + nb + lo0);
      async_ld16(bg1, Bs + nb + lo1);
      ag0 += 32; ag1 += 32; bg0 += 32; bg1 += 32;
    }

    const char* pA = (const char*)As + (cur << 13) + afb;
    const char* pB = (const char*)Bs + (cur << 13) + bfb;
    bf16x8 af[4], bfr[4];
#pragma unroll
    for (int i = 0; i < 4; ++i) af[i] = *(const bf16x8*)(pA + i * 1024);
#pragma unroll
    for (int j = 0; j < 4; ++j) bfr[j] = *(const bf16x8*)(pB + j * 1024);
#pragma unroll
    for (int i = 0; i < 4; ++i)
#pragma unroll
      for (int j = 0; j < 4; ++j)
        acc[i][j] = MFMA16(af[i], bfr[j], acc[i][j]);

    __syncthreads();
  }

#pragma unroll
  for (int i = 0; i < 4; ++i) {
    const int m = m0 + wm + i * 16 + quad * 4;
#pragma unroll
    for (int j = 0; j < 4; ++j) {
      const int n = n0 + wn + j * 16 + l15;
#pragma unroll
      for (int r = 0; r < 4; ++r)
        C[(size_t)(m + r) * N + n] = acc[i][j][r];
    }
  }
}

// ---------------------------------------------------------------------------
// Projection GEMM, fp32-B fallback. grid (8,64).
// ---------------------------------------------------------------------------
__global__ __launch_bounds__(256, 2)
void gemm_proj_f(const bf16* __restrict__ A, const float* __restrict__ B,
                 float* __restrict__ C) {
  __shared__ __align__(16) bf16 As[128 * 32];
  __shared__ __align__(16) bf16 Bs[128 * 32];
  const int K = 1024, N = 1024;

  const int tid  = threadIdx.x;
  const int lane = tid & 63;
  const int wave = tid >> 6;
  const int quad = lane >> 4;
  const int l15  = lane & 15;
  const int wm   = (wave >> 1) * 64;
  const int wn   = (wave & 1) * 64;

  const int lin = (int)blockIdx.x + (int)blockIdx.y * 8;
  const int xcd = lin & 7;
  const int sl  = lin >> 3;
  const int m0  = (xcd * 8 + (sl & 7)) * 128;
  const int n0  = (sl >> 3) * 128;

  f32x4 acc[4][4];
#pragma unroll
  for (int i = 0; i < 4; ++i)
#pragma unroll
    for (int j = 0; j < 4; ++j) acc[i][j] = f32x4{0.f, 0.f, 0.f, 0.f};

  const int r0 = tid >> 2;
  const int c0 = (tid & 3) * 8;
  const size_t aoff0 = (size_t)(m0 + r0) * K + c0;
  const size_t aoff1 = (size_t)(m0 + 64 + r0) * K + c0;
  const size_t boff0 = (size_t)(n0 + r0) * K + c0;
  const size_t boff1 = (size_t)(n0 + 64 + r0) * K + c0;

  for (int k0 = 0; k0 < K; k0 += 32) {
    bf16x8 va0 = *(const bf16x8*)(A + aoff0 + k0);
    bf16x8 va1 = *(const bf16x8*)(A + aoff1 + k0);
    bf16x8 vb0 = cvt8(B + boff0 + k0);
    bf16x8 vb1 = cvt8(B + boff1 + k0);
    __syncthreads();
    *(bf16x8*)(As + tid * 8)        = va0;
    *(bf16x8*)(As + 2048 + tid * 8) = va1;
    *(bf16x8*)(Bs + tid * 8)        = vb0;
    *(bf16x8*)(Bs + 2048 + tid * 8) = vb1;
    __syncthreads();

    bf16x8 af[4], bfr[4];
#pragma unroll
    for (int i = 0; i < 4; ++i)
      af[i] = *(const bf16x8*)(As + (wm + i * 16 + l15) * 32 + quad * 8);
#pragma unroll
    for (int j = 0; j < 4; ++j)
      bfr[j] = *(const bf16x8*)(Bs + (wn + j * 16 + l15) * 32 + quad * 8);
#pragma unroll
    for (int i = 0; i < 4; ++i)
#pragma unroll
      for (int j = 0; j < 4; ++j)
        acc[i][j] = MFMA16(af[i], bfr[j], acc[i][j]);
  }

#pragma unroll
  for (int i = 0; i < 4; ++i) {
    const int m = m0 + wm + i * 16 + quad * 4;
#pragma unroll
    for (int j = 0; j < 4; ++j) {
      const int n = n0 + wn + j * 16 + l15;
#pragma unroll
      for (int r = 0; r < 4; ++r)
        C[(size_t)(m + r) * N + n] = acc[i][j][r];
    }
  }
}

// ---------------------------------------------------------------------------
extern "C" void kernel_launch(void* const* d_in, const int* in_sizes, int n_in,
                              void* d_out, int out_size, void* d_ws, size_t ws_size,
                              hipStream_t stream) {
  const float* x  = nullptr;   // 8388608 elems
  const float* wq = nullptr;   // 3145728
  const float* wp = nullptr;   // 1048576
  for (int i = 0; i < n_in; ++i) {
    if      (in_sizes[i] == 8388608) x  = (const float*)d_in[i];
    else if (in_sizes[i] == 3145728) wq = (const float*)d_in[i];
    else if (in_sizes[i] == 1048576) wp = (const float*)d_in[i];
  }
  if (!x || !wq || !wp) {
    x = (const float*)d_in[0]; wq = (const float*)d_in[1]; wp = (const float*)d_in[2];
  }

  float* out = (float*)d_out;            // [4,2048,1024] fp32, written once
  const size_t NE = (size_t)4 * 16 * 2048 * 64;  // 8388608
  bf16* kb = (bf16*)d_ws;                // base 64MB: K, V^T, Q, y
  bf16* vb = kb + NE;                    // V^T: [bh][64][2048]
  bf16* qb = vb + NE;
  bf16* yb = qb + NE;
  bf16* xb  = yb + NE;                   // 8388608 elems
  bf16* wqb = xb + 8388608;              // 3145728
  bf16* wpb = wqb + 3145728;             // 1048576
  const size_t need = (4 * NE + 8388608 + 3145728 + 1048576) * sizeof(bf16);
  const bool ext = ws_size >= need;      // deterministic -> graph-safe

  if (ext) {
    cvt_all<<<6144, 256, 0, stream>>>(x, wq, wp, xb, wqb, wpb);
    gemm_qkv_a<<<dim3(24, 64), 256, 0, stream>>>(xb, wqb, qb, kb, vb);
  } else {
    gemm_qkv_f<<<dim3(24, 64), 256, 0, stream>>>(x, wq, qb, kb, vb);
  }

  attn<<<dim3(16, 64), 256, 0, stream>>>(qb, kb, vb, yb);

  if (ext) {
    gemm_proj_a<<<dim3(8, 64), 256, 0, stream>>>(yb, wpb, out);
  } else {
    gemm_proj_f<<<dim3(8, 64), 256, 0, stream>>>(yb, wp, out);
  }
}

// Round 8
// 240.973 us; speedup vs baseline: 1.7668x; 1.0027x over previous
//
#include <hip/hip_runtime.h>
#include <cstdint>
#include <cstddef>

// Pipeline v13. B=4, T=2048, D=1024, H=16, HD=64. Inputs fp32, output fp32.
// R7 bisect: GEMM v11 rewrite good, v11 attn rewrite bad. This round: attn
// only, attack the VGPR-cap-forced rematerialization (R5: ~420 VALU/tile,
// VGPR=56 under a 64-reg cap):
//   - launch_bounds (256,4) -> (256,3): cap 64 -> 85 VGPR.
//   - manually hoist K/V fragment byte offsets (fo0/fo1, shared formula) and
//     P-write offsets (pwo) out of the kv loop; bit-identical addresses.
// Everything else byte-identical to the R7 passing kernel.

typedef __bf16 bf16;
typedef __bf16 bf16x4 __attribute__((ext_vector_type(4)));
typedef __bf16 bf16x8 __attribute__((ext_vector_type(8)));
typedef float  f32x4  __attribute__((ext_vector_type(4)));
typedef float  fvec4  __attribute__((ext_vector_type(4)));
typedef unsigned u32x2 __attribute__((ext_vector_type(2)));

typedef __attribute__((address_space(1))) const void global_cv;
typedef __attribute__((address_space(3))) void lds_v;

#define MFMA16(a, b, c) __builtin_amdgcn_mfma_f32_16x16x32_bf16((a), (b), (c), 0, 0, 0)

// Q scale: 1/sqrt(64) * log2(e)  (softmax done in exp2 domain)
#define QSCALE 0.18033688f

__device__ __forceinline__ void async_ld16(const bf16* g, bf16* l) {
  __builtin_amdgcn_global_load_lds((global_cv*)g, (lds_v*)l, 16, 0, 0);
}

// XOR chunk swizzle for [rows][64] bf16 LDS tiles (attn staging + frag reads).
__device__ __forceinline__ int swz_off(int row, int col) {
  int sr = (row & 7) ^ ((row >> 3) & 7);
  return row * 64 + ((((col >> 3) ^ sr) & 7) * 8) + (col & 7);
}

// packed f32x2 -> bf16x2
__device__ __forceinline__ unsigned cvt_pk(float lo, float hi) {
  unsigned r;
  asm("v_cvt_pk_bf16_f32 %0, %1, %2" : "=v"(r) : "v"(lo), "v"(hi));
  return r;
}

// exact v_exp_f32 (2^x), no libm fixup path
__device__ __forceinline__ float exp2_fast(float x) {
  float r;
  asm("v_exp_f32 %0, %1" : "=v"(r) : "v"(x));
  return r;
}

__device__ __forceinline__ bf16x8 cvt8(const float* p) {
  fvec4 u = *(const fvec4*)p;
  fvec4 v = *(const fvec4*)(p + 4);
  bf16x8 r;
  r[0] = (bf16)u[0]; r[1] = (bf16)u[1]; r[2] = (bf16)u[2]; r[3] = (bf16)u[3];
  r[4] = (bf16)v[0]; r[5] = (bf16)v[1]; r[6] = (bf16)v[2]; r[7] = (bf16)v[3];
  return r;
}

// ---------------------------------------------------------------------------
// Fused fp32 -> bf16 bulk convert (8 elems/thread). grid 6144 x 256 exact.
// ---------------------------------------------------------------------------
__global__ void cvt_all(const float* __restrict__ x, const float* __restrict__ wq,
                        const float* __restrict__ wp, bf16* __restrict__ xb,
                        bf16* __restrict__ wqb, bf16* __restrict__ wpb) {
  int i = blockIdx.x * 256 + threadIdx.x;
  const float* s;
  bf16* d;
  int off;
  if (i < 1048576)      { s = x;  d = xb;  off = i; }
  else if (i < 1441792) { s = wq; d = wqb; off = i - 1048576; }
  else                  { s = wp; d = wpb; off = i - 1441792; }
  *(bf16x8*)(d + (size_t)off * 8) = cvt8(s + (size_t)off * 8);
}

// ---------------------------------------------------------------------------
// Shared epilogue: Q,K as [bh][t][64]; V TRANSPOSED as [bh][d][t].
// ---------------------------------------------------------------------------
__device__ __forceinline__ void qkv_scatter(const f32x4 acc[4][4], int m0, int n0,
                                            int wm, int wn, int quad, int l15,
                                            bf16* Qo, bf16* Ko, bf16* Vo) {
  const int which = n0 >> 10;  // 0=Q 1=K 2=V
  if (which == 2) {
#pragma unroll
    for (int i = 0; i < 4; ++i) {
      const int m = m0 + wm + i * 16 + quad * 4;
      const int b = m >> 11;
      const int t = m & 2047;
#pragma unroll
      for (int j = 0; j < 4; ++j) {
        const int n1 = (n0 + wn + j * 16 + l15) & 1023;
        const int h  = n1 >> 6;
        const int d  = n1 & 63;
        bf16x4 v;
#pragma unroll
        for (int r = 0; r < 4; ++r) v[r] = (bf16)acc[i][j][r];
        *(bf16x4*)(Vo + ((size_t)(b * 16 + h) * 64 + d) * 2048 + t) = v;
      }
    }
    return;
  }
  bf16* dst = (which == 0) ? Qo : Ko;
  const float scale = (which == 0) ? QSCALE : 1.0f;
#pragma unroll
  for (int i = 0; i < 4; ++i) {
    const int m = m0 + wm + i * 16 + quad * 4;
#pragma unroll
    for (int j = 0; j < 4; ++j) {
      const int n  = n0 + wn + j * 16 + l15;
      const int n1 = n & 1023;
      const int h  = n1 >> 6;
      const int d  = n1 & 63;
#pragma unroll
      for (int r = 0; r < 4; ++r) {
        const int mm = m + r;
        const int b  = mm >> 11;
        const int t  = mm & 2047;
        dst[(((size_t)(b * 16 + h)) * 2048 + t) * 64 + d] =
            (bf16)(acc[i][j][r] * scale);
      }
    }
  }
}

// ---------------------------------------------------------------------------
// QKV GEMM, bf16, double-buffered async staging (v11 form). grid (24,64).
// ---------------------------------------------------------------------------
__global__ __launch_bounds__(256, 3)
void gemm_qkv_a(const bf16* __restrict__ A, const bf16* __restrict__ B,
                bf16* __restrict__ Qo, bf16* __restrict__ Ko,
                bf16* __restrict__ Vo) {
  __shared__ __align__(16) bf16 As[2 * 128 * 32];
  __shared__ __align__(16) bf16 Bs[2 * 128 * 32];
  const int K = 1024;

  const int tid  = threadIdx.x;
  const int lane = tid & 63;
  const int wave = tid >> 6;
  const int quad = lane >> 4;
  const int l15  = lane & 15;
  const int wm   = (wave >> 1) * 64;
  const int wn   = (wave & 1) * 64;

  const int lin = (int)blockIdx.x + (int)blockIdx.y * 24;
  const int xcd = lin & 7;
  const int sl  = lin >> 3;
  const int n0  = (xcd * 3 + (sl % 3)) * 128;
  const int m0  = (sl / 3) * 128;

  f32x4 acc[4][4];
#pragma unroll
  for (int i = 0; i < 4; ++i)
#pragma unroll
    for (int j = 0; j < 4; ++j) acc[i][j] = f32x4{0.f, 0.f, 0.f, 0.f};

  const int r0 = tid >> 2;
  const int c0 = (tid & 3) * 8;
  const bf16* ag0 = A + (size_t)(m0 + r0) * K + c0;
  const bf16* ag1 = A + (size_t)(m0 + 64 + r0) * K + c0;
  const bf16* bg0 = B + (size_t)(n0 + r0) * K + c0;
  const bf16* bg1 = B + (size_t)(n0 + 64 + r0) * K + c0;
  const int lo0 = (wave * 64) * 8;
  const int lo1 = (256 + wave * 64) * 8;

  const int afb = (wm + l15) * 64 + quad * 16;
  const int bfb = (wn + l15) * 64 + quad * 16;

  async_ld16(ag0, As + lo0);
  async_ld16(ag1, As + lo1);
  async_ld16(bg0, Bs + lo0);
  async_ld16(bg1, Bs + lo1);
  ag0 += 32; ag1 += 32; bg0 += 32; bg1 += 32;
  __syncthreads();

  for (int it = 0; it < 32; ++it) {
    const int cur = it & 1;
    if (it < 31) {
      const int nb = (cur ^ 1) << 12;
      async_ld16(ag0, As + nb + lo0);
      async_ld16(ag1, As + nb + lo1);
      async_ld16(bg0, Bs + nb + lo0);
      async_ld16(bg1, Bs + nb + lo1);
      ag0 += 32; ag1 += 32; bg0 += 32; bg1 += 32;
    }

    const char* pA = (const char*)As + (cur << 13) + afb;
    const char* pB = (const char*)Bs + (cur << 13) + bfb;
    bf16x8 af[4], bfr[4];
#pragma unroll
    for (int i = 0; i < 4; ++i) af[i] = *(const bf16x8*)(pA + i * 1024);
#pragma unroll
    for (int j = 0; j < 4; ++j) bfr[j] = *(const bf16x8*)(pB + j * 1024);
#pragma unroll
    for (int i = 0; i < 4; ++i)
#pragma unroll
      for (int j = 0; j < 4; ++j)
        acc[i][j] = MFMA16(af[i], bfr[j], acc[i][j]);

    __syncthreads();
  }
  qkv_scatter(acc, m0, n0, wm, wn, quad, l15, Qo, Ko, Vo);
}

// ---------------------------------------------------------------------------
// QKV GEMM, fp32 cvt8 register-staging fallback. grid (24,64).
// ---------------------------------------------------------------------------
__global__ __launch_bounds__(256, 2)
void gemm_qkv_f(const float* __restrict__ A, const float* __restrict__ B,
                bf16* __restrict__ Qo, bf16* __restrict__ Ko,
                bf16* __restrict__ Vo) {
  __shared__ __align__(16) bf16 As[128 * 32];
  __shared__ __align__(16) bf16 Bs[128 * 32];
  const int K = 1024;

  const int tid  = threadIdx.x;
  const int lane = tid & 63;
  const int wave = tid >> 6;
  const int quad = lane >> 4;
  const int l15  = lane & 15;
  const int wm   = (wave >> 1) * 64;
  const int wn   = (wave & 1) * 64;

  const int lin = (int)blockIdx.x + (int)blockIdx.y * 24;
  const int xcd = lin & 7;
  const int sl  = lin >> 3;
  const int n0  = (xcd * 3 + (sl % 3)) * 128;
  const int m0  = (sl / 3) * 128;

  f32x4 acc[4][4];
#pragma unroll
  for (int i = 0; i < 4; ++i)
#pragma unroll
    for (int j = 0; j < 4; ++j) acc[i][j] = f32x4{0.f, 0.f, 0.f, 0.f};

  const int r0 = tid >> 2;
  const int c0 = (tid & 3) * 8;
  const size_t aoff0 = (size_t)(m0 + r0) * K + c0;
  const size_t aoff1 = (size_t)(m0 + 64 + r0) * K + c0;
  const size_t boff0 = (size_t)(n0 + r0) * K + c0;
  const size_t boff1 = (size_t)(n0 + 64 + r0) * K + c0;

  for (int k0 = 0; k0 < K; k0 += 32) {
    bf16x8 va0 = cvt8(A + aoff0 + k0);
    bf16x8 va1 = cvt8(A + aoff1 + k0);
    bf16x8 vb0 = cvt8(B + boff0 + k0);
    bf16x8 vb1 = cvt8(B + boff1 + k0);
    __syncthreads();
    *(bf16x8*)(As + tid * 8)        = va0;
    *(bf16x8*)(As + 2048 + tid * 8) = va1;
    *(bf16x8*)(Bs + tid * 8)        = vb0;
    *(bf16x8*)(Bs + 2048 + tid * 8) = vb1;
    __syncthreads();

    bf16x8 af[4], bfr[4];
#pragma unroll
    for (int i = 0; i < 4; ++i)
      af[i] = *(const bf16x8*)(As + (wm + i * 16 + l15) * 32 + quad * 8);
#pragma unroll
    for (int j = 0; j < 4; ++j)
      bfr[j] = *(const bf16x8*)(Bs + (wn + j * 16 + l15) * 32 + quad * 8);
#pragma unroll
    for (int i = 0; i < 4; ++i)
#pragma unroll
      for (int j = 0; j < 4; ++j)
        acc[i][j] = MFMA16(af[i], bfr[j], acc[i][j]);
  }
  qkv_scatter(acc, m0, n0, wm, wn, quad, l15, Qo, Ko, Vo);
}

// ---------------------------------------------------------------------------
// Flash attention — R7 passing version + (256,3) cap + hoisted frag/P offsets.
// grid (16,64), XCD-clustered remap; q-tiles {p, 31-p}.
// ---------------------------------------------------------------------------
__global__ __launch_bounds__(256, 3)
void attn(const bf16* __restrict__ Q, const bf16* __restrict__ Kk,
          const bf16* __restrict__ Vt, bf16* __restrict__ Y) {
  __shared__ __align__(16) bf16 Ks[2][64 * 64];   // [kv][d] swizzled
  __shared__ __align__(16) bf16 Vs[2][64 * 64];   // [d][kv] swizzled
  __shared__ __align__(16) bf16 Ps[4 * 16 * 64];  // per-wave P strips

  const int tid  = threadIdx.x;
  const int wave = tid >> 6;
  const int lane = tid & 63;
  const int quad = lane >> 4;
  const int l15  = lane & 15;

  const int lin  = (int)blockIdx.x + ((int)blockIdx.y << 4);
  const int slot = lin >> 3;
  const int bh   = (lin & 7) * 8 + (slot >> 4);
  const int p    = slot & 15;
  const int b    = bh >> 4;
  const int h    = bh & 15;

  const bf16* Qb = Q  + (size_t)bh * (2048 * 64);
  const bf16* Kb = Kk + (size_t)bh * (2048 * 64);   // [t][64]
  const bf16* Vb = Vt + (size_t)bh * (2048 * 64);   // [64][2048] (transposed)
  char* Pw = (char*)(Ps + wave * (16 * 64));        // 2KB per-wave strip

  const int r0s = wave * 8 + (lane >> 3);       // issue-0 row (0..31)
  const int r1s = r0s + 32;                     // issue-1 row (32..63)
  const int qch = lane & 7;
  const int co0 = (((qch ^ ((r0s & 7) ^ ((r0s >> 3) & 7)))) & 7) * 8;
  const int co1 = (((qch ^ ((r1s & 7) ^ ((r1s >> 3) & 7)))) & 7) * 8;
  const bf16* kg0 = Kb + (size_t)r0s * 64 + co0;    // + k0*64 per tile
  const bf16* kg1 = Kb + (size_t)r1s * 64 + co1;
  const bf16* vg0 = Vb + (size_t)r0s * 2048 + co0;  // + k0 per tile
  const bf16* vg1 = Vb + (size_t)r1s * 2048 + co1;
  const int ldsw = wave * 512;                  // wave-uniform elem offset

  // P strip addressing (bytes): row = l15 (128B), 16B chunk C ^= (l15&7).
  const int psx   = l15 & 7;
  const int prowb = l15 * 128;
  const int pr0   = prowb + ((quad ^ psx) << 4);        // PV A-frag k 0..31
  const int pr1   = prowb + (((4 + quad) ^ psx) << 4);  // PV A-frag k 32..63

  // Hoisted K/V fragment byte offsets (identical formula for K and V tiles:
  // row = j*16+l15, cols quad*8 and 32+quad*8). Statically indexed -> regs.
  int fo0[4], fo1[4];
#pragma unroll
  for (int j = 0; j < 4; ++j) {
    const int kvr = j * 16 + l15;
    fo0[j] = swz_off(kvr, quad * 8) * 2;
    fo1[j] = swz_off(kvr, 32 + quad * 8) * 2;
  }
  // Hoisted P-strip write offsets (k = 16j + 4*quad .. +3).
  int pwo[4];
#pragma unroll
  for (int j = 0; j < 4; ++j)
    pwo[j] = prowb + ((((2 * j + (quad >> 1)) ^ psx) << 4) | ((quad & 1) << 3));

  const float NEG = -1e30f;

#pragma unroll 1
  for (int pass = 0; pass < 2; ++pass) {
    const int qt = pass ? (31 - p) : p;
    const int q0 = qt * 64;

    const bf16* qp = Qb + (size_t)(q0 + wave * 16 + l15) * 64 + quad * 8;
    bf16x8 qa0 = *(const bf16x8*)qp;
    bf16x8 qa1 = *(const bf16x8*)(qp + 32);

    f32x4 l4 = {0.f, 0.f, 0.f, 0.f};
    f32x4 o[4];
#pragma unroll
    for (int j = 0; j < 4; ++j) o[j] = f32x4{0.f, 0.f, 0.f, 0.f};

    // prologue: stage kv-tile 0 into buffer 0
    async_ld16(kg0, Ks[0] + ldsw);
    async_ld16(kg1, Ks[0] + 2048 + ldsw);
    async_ld16(vg0, Vs[0] + ldsw);
    async_ld16(vg1, Vs[0] + 2048 + ldsw);
    __syncthreads();

#pragma unroll 1
    for (int kt = 0; kt <= qt; ++kt) {
      const int cur = kt & 1;
      const int k0  = kt * 64;

      if (kt < qt) {
        const int kn = k0 + 64;
        async_ld16(kg0 + (size_t)kn * 64, Ks[cur ^ 1] + ldsw);
        async_ld16(kg1 + (size_t)kn * 64, Ks[cur ^ 1] + 2048 + ldsw);
        async_ld16(vg0 + kn, Vs[cur ^ 1] + ldsw);
        async_ld16(vg1 + kn, Vs[cur ^ 1] + 2048 + ldsw);
      }

      const char* kc = (const char*)Ks[cur];

      // S^T = K Q^T (log2 domain via QSCALE): lane -> q = l15,
      // k = k0 + 16j + 4*quad + r.
      f32x4 s[4];
      __builtin_amdgcn_s_setprio(1);
#pragma unroll
      for (int j = 0; j < 4; ++j) {
        bf16x8 k0f = *(const bf16x8*)(kc + fo0[j]);
        bf16x8 k1f = *(const bf16x8*)(kc + fo1[j]);
        f32x4 z = {0.f, 0.f, 0.f, 0.f};
        z = MFMA16(k0f, qa0, z);
        z = MFMA16(k1f, qa1, z);
        s[j] = z;
      }
      __builtin_amdgcn_s_setprio(0);

      if (kt == qt) {  // diagonal: causal mask (k_local > q_local)
        const int qloc = wave * 16 + l15;
#pragma unroll
        for (int j = 0; j < 4; ++j) {
#pragma unroll
          for (int r = 0; r < 4; ++r) {
            if (16 * j + 4 * quad + r > qloc) s[j][r] = NEG;
          }
        }
      }

      // p = exp2(s) via v_exp_f32; accumulate l partials
#pragma unroll
      for (int j = 0; j < 4; ++j) {
#pragma unroll
        for (int r = 0; r < 4; ++r) s[j][r] = exp2_fast(s[j][r]);
        l4 += s[j];
      }

      // P strip: 4 packed 8B writes (hoisted offsets).
#pragma unroll
      for (int j = 0; j < 4; ++j) {
        u32x2 pk;
        pk[0] = cvt_pk(s[j][0], s[j][1]);
        pk[1] = cvt_pk(s[j][2], s[j][3]);
        *(u32x2*)(Pw + pwo[j]) = pk;
      }

      bf16x8 pf0 = *(const bf16x8*)(Pw + pr0);
      bf16x8 pf1 = *(const bf16x8*)(Pw + pr1);

      // PV from V^T tile (same hoisted offsets as K)
      const char* vc = (const char*)Vs[cur];
      __builtin_amdgcn_s_setprio(1);
#pragma unroll
      for (int j = 0; j < 4; ++j) {
        bf16x8 vf0 = *(const bf16x8*)(vc + fo0[j]);
        bf16x8 vf1 = *(const bf16x8*)(vc + fo1[j]);
        o[j] = MFMA16(pf0, vf0, o[j]);
        o[j] = MFMA16(pf1, vf1, o[j]);
      }
      __builtin_amdgcn_s_setprio(0);

      __syncthreads();  // drains staging (vmcnt) + protects both buffers
    }

    // l: fold 4 components, reduce across quads, redistribute.
    float lf = (l4[0] + l4[1]) + (l4[2] + l4[3]);
    lf += __shfl_xor(lf, 16);
    lf += __shfl_xor(lf, 32);
    float inv[4];
#pragma unroll
    for (int r = 0; r < 4; ++r) inv[r] = 1.0f / __shfl(lf, quad * 4 + r);

#pragma unroll
    for (int j = 0; j < 4; ++j) {
      const int dcol = h * 64 + j * 16 + l15;
#pragma unroll
      for (int r = 0; r < 4; ++r) {
        const int trow = q0 + wave * 16 + quad * 4 + r;
        Y[((size_t)b * 2048 + trow) * 1024 + dcol] = (bf16)(o[j][r] * inv[r]);
      }
    }
  }
}

// ---------------------------------------------------------------------------
// Projection GEMM, bf16, double-buffered async staging (v11 form). grid (8,64).
// ---------------------------------------------------------------------------
__global__ __launch_bounds__(256, 3)
void gemm_proj_a(const bf16* __restrict__ A, const bf16* __restrict__ B,
                 float* __restrict__ C) {
  __shared__ __align__(16) bf16 As[2 * 128 * 32];
  __shared__ __align__(16) bf16 Bs[2 * 128 * 32];
  const int K = 1024, N = 1024;

  const int tid  = threadIdx.x;
  const int lane = tid & 63;
  const int wave = tid >> 6;
  const int quad = lane >> 4;
  const int l15  = lane & 15;
  const int wm   = (wave >> 1) * 64;
  const int wn   = (wave & 1) * 64;

  const int lin = (int)blockIdx.x + (int)blockIdx.y * 8;
  const int xcd = lin & 7;
  const int sl  = lin >> 3;
  const int m0  = (xcd * 8 + (sl & 7)) * 128;
  const int n0  = (sl >> 3) * 128;

  f32x4 acc[4][4];
#pragma unroll
  for (int i = 0; i < 4; ++i)
#pragma unroll
    for (int j = 0; j < 4; ++j) acc[i][j] = f32x4{0.f, 0.f, 0.f, 0.f};

  const int r0 = tid >> 2;
  const int c0 = (tid & 3) * 8;
  const bf16* ag0 = A + (size_t)(m0 + r0) * K + c0;
  const bf16* ag1 = A + (size_t)(m0 + 64 + r0) * K + c0;
  const bf16* bg0 = B + (size_t)(n0 + r0) * K + c0;
  const bf16* bg1 = B + (size_t)(n0 + 64 + r0) * K + c0;
  const int lo0 = (wave * 64) * 8;
  const int lo1 = (256 + wave * 64) * 8;

  const int afb = (wm + l15) * 64 + quad * 16;
  const int bfb = (wn + l15) * 64 + quad * 16;

  async_ld16(ag0, As + lo0);
  async_ld16(ag1, As + lo1);
  async_ld16(bg0, Bs + lo0);
  async_ld16(bg1, Bs + lo1);
  ag0 += 32; ag1 += 32; bg0 += 32; bg1 += 32;
  __syncthreads();

  for (int it = 0; it < 32; ++it) {
    const int cur = it & 1;
    if (it < 31) {
      const int nb = (cur ^ 1) << 12;
      async_ld16(ag0, As + nb + lo0);
      async_ld16(ag1, As + nb + lo1);
      async_ld16(bg0, Bs + nb + lo0);
      async_ld16(bg1, Bs + nb + lo1);
      ag0 += 32; ag1 += 32; bg0 += 32; bg1 += 32;
    }

    const char* pA = (const char*)As + (cur << 13) + afb;
    const char* pB = (const char*)Bs + (cur << 13) + bfb;
    bf16x8 af[4], bfr[4];
#pragma unroll
    for (int i = 0; i < 4; ++i) af[i] = *(const bf16x8*)(pA + i * 1024);
#pragma unroll
    for (int j = 0; j < 4; ++j) bfr[j] = *(const bf16x8*)(pB + j * 1024);
#pragma unroll
    for (int i = 0; i < 4; ++i)
#pragma unroll
      for (int j = 0; j < 4; ++j)
        acc[i][j] = MFMA16(af[i], bfr[j], acc[i][j]);

    __syncthreads();
  }

#pragma unroll
  for (int i = 0; i < 4; ++i) {
    const int m = m0 + wm + i * 16 + quad * 4;
#pragma unroll
    for (int j = 0; j < 4; ++j) {
      const int n = n0 + wn + j * 16 + l15;
#pragma unroll
      for (int r = 0; r < 4; ++r)
        C[(size_t)(m + r) * N + n] = acc[i][j][r];
    }
  }
}

// ---------------------------------------------------------------------------
// Projection GEMM, fp32-B fallback. grid (8,64).
// ---------------------------------------------------------------------------
__global__ __launch_bounds__(256, 2)
void gemm_proj_f(const bf16* __restrict__ A, const float* __restrict__ B,
                 float* __restrict__ C) {
  __shared__ __align__(16) bf16 As[128 * 32];
  __shared__ __align__(16) bf16 Bs[128 * 32];
  const int K = 1024, N = 1024;

  const int tid  = threadIdx.x;
  const int lane = tid & 63;
  const int wave = tid >> 6;
  const int quad = lane >> 4;
  const int l15  = lane & 15;
  const int wm   = (wave >> 1) * 64;
  const int wn   = (wave & 1) * 64;

  const int lin = (int)blockIdx.x + (int)blockIdx.y * 8;
  const int xcd = lin & 7;
  const int sl  = lin >> 3;
  const int m0  = (xcd * 8 + (sl & 7)) * 128;
  const int n0  = (sl >> 3) * 128;

  f32x4 acc[4][4];
#pragma unroll
  for (int i = 0; i < 4; ++i)
#pragma unroll
    for (int j = 0; j < 4; ++j) acc[i][j] = f32x4{0.f, 0.f, 0.f, 0.f};

  const int r0 = tid >> 2;
  const int c0 = (tid & 3) * 8;
  const size_t aoff0 = (size_t)(m0 + r0) * K + c0;
  const size_t aoff1 = (size_t)(m0 + 64 + r0) * K + c0;
  const size_t boff0 = (size_t)(n0 + r0) * K + c0;
  const size_t boff1 = (size_t)(n0 + 64 + r0) * K + c0;

  for (int k0 = 0; k0 < K; k0 += 32) {
    bf16x8 va0 = *(const bf16x8*)(A + aoff0 + k0);
    bf16x8 va1 = *(const bf16x8*)(A + aoff1 + k0);
    bf16x8 vb0 = cvt8(B + boff0 + k0);
    bf16x8 vb1 = cvt8(B + boff1 + k0);
    __syncthreads();
    *(bf16x8*)(As + tid * 8)        = va0;
    *(bf16x8*)(As + 2048 + tid * 8) = va1;
    *(bf16x8*)(Bs + tid * 8)        = vb0;
    *(bf16x8*)(Bs + 2048 + tid * 8) = vb1;
    __syncthreads();

    bf16x8 af[4], bfr[4];
#pragma unroll
    for (int i = 0; i < 4; ++i)
      af[i] = *(const bf16x8*)(As + (wm + i * 16 + l15) * 32 + quad * 8);
#pragma unroll
    for (int j = 0; j < 4; ++j)
      bfr[j] = *(const bf16x8*)(Bs + (wn + j * 16 + l15) * 32 + quad * 8);
#pragma unroll
    for (int i = 0; i < 4; ++i)
#pragma unroll
      for (int j = 0; j < 4; ++j)
        acc[i][j] = MFMA16(af[i], bfr[j], acc[i][j]);
  }

#pragma unroll
  for (int i = 0; i < 4; ++i) {
    const int m = m0 + wm + i * 16 + quad * 4;
#pragma unroll
    for (int j = 0; j < 4; ++j) {
      const int n = n0 + wn + j * 16 + l15;
#pragma unroll
      for (int r = 0; r < 4; ++r)
        C[(size_t)(m + r) * N + n] = acc[i][j][r];
    }
  }
}

// ---------------------------------------------------------------------------
extern "C" void kernel_launch(void* const* d_in, const int* in_sizes, int n_in,
                              void* d_out, int out_size, void* d_ws, size_t ws_size,
                              hipStream_t stream) {
  const float* x  = nullptr;   // 8388608 elems
  const float* wq = nullptr;   // 3145728
  const float* wp = nullptr;   // 1048576
  for (int i = 0; i < n_in; ++i) {
    if      (in_sizes[i] == 8388608) x  = (const float*)d_in[i];
    else if (in_sizes[i] == 3145728) wq = (const float*)d_in[i];
    else if (in_sizes[i] == 1048576) wp = (const float*)d_in[i];
  }
  if (!x || !wq || !wp) {
    x = (const float*)d_in[0]; wq = (const float*)d_in[1]; wp = (const float*)d_in[2];
  }

  float* out = (float*)d_out;            // [4,2048,1024] fp32, written once
  const size_t NE = (size_t)4 * 16 * 2048 * 64;  // 8388608
  bf16* kb = (bf16*)d_ws;                // base 64MB: K, V^T, Q, y
  bf16* vb = kb + NE;                    // V^T: [bh][64][2048]
  bf16* qb = vb + NE;
  bf16* yb = qb + NE;
  bf16* xb  = yb + NE;                   // 8388608 elems
  bf16* wqb = xb + 8388608;              // 3145728
  bf16* wpb = wqb + 3145728;             // 1048576
  const size_t need = (4 * NE + 8388608 + 3145728 + 1048576) * sizeof(bf16);
  const bool ext = ws_size >= need;      // deterministic -> graph-safe

  if (ext) {
    cvt_all<<<6144, 256, 0, stream>>>(x, wq, wp, xb, wqb, wpb);
    gemm_qkv_a<<<dim3(24, 64), 256, 0, stream>>>(xb, wqb, qb, kb, vb);
  } else {
    gemm_qkv_f<<<dim3(24, 64), 256, 0, stream>>>(x, wq, qb, kb, vb);
  }

  attn<<<dim3(16, 64), 256, 0, stream>>>(qb, kb, vb, yb);

  if (ext) {
    gemm_proj_a<<<dim3(8, 64), 256, 0, stream>>>(yb, wpb, out);
  } else {
    gemm_proj_f<<<dim3(8, 64), 256, 0, stream>>>(yb, wp, out);
  }
}